// Round 4
// baseline (365.274 us; speedup 1.0000x reference)
//
#include <hip/hip_runtime.h>
#include <math.h>

// Problem constants
#define B_   4
#define S_   2048
#define D_   1024
#define H_   1024
#define NROW 2048
#define TOTX 8388608.0f            // B_*S_*D_ elements of x

typedef _Float16 f16x8 __attribute__((ext_vector_type(8)));
typedef float f32x4 __attribute__((ext_vector_type(4)));

__device__ __forceinline__ unsigned short f2h(float f) {
  _Float16 h = (_Float16)f;                       // v_cvt_f16_f32, RNE
  return __builtin_bit_cast(unsigned short, h);
}

// async global->LDS, 16B per lane, lands at ldsbase + lane*16
#define GLD16(gp, lp)                                                            \
  __builtin_amdgcn_global_load_lds(                                              \
      (__attribute__((address_space(1))) void*)(gp),                             \
      (__attribute__((address_space(3))) void*)(lp), 16, 0, 0)

// ---------------------------------------------------------------------------
// fused float->f16 conversion + abs-sum for x (one pass over 32 MB)
// ---------------------------------------------------------------------------
__global__ __launch_bounds__(256) void f2h_abs_kernel(const float* __restrict__ in,
                                                      unsigned short* __restrict__ out,
                                                      float* absOut, int n4) {
  int i0 = blockIdx.x * 256 + threadIdx.x;
  int stride = gridDim.x * 256;
  float s = 0.f;
  for (int i = i0; i < n4; i += stride) {
    float4 v = ((const float4*)in)[i];
    ushort4 o;
    o.x = f2h(v.x); o.y = f2h(v.y); o.z = f2h(v.z); o.w = f2h(v.w);
    ((ushort4*)out)[i] = o;
    s += fabsf(v.x) + fabsf(v.y) + fabsf(v.z) + fabsf(v.w);
  }
#pragma unroll
  for (int off = 32; off; off >>= 1) s += __shfl_xor(s, off);
  __shared__ float red[4];
  if ((threadIdx.x & 63) == 0) red[threadIdx.x >> 6] = s;
  __syncthreads();
  if (threadIdx.x == 0) atomicAdd(absOut, red[0] + red[1] + red[2] + red[3]);
}

// ---------------------------------------------------------------------------
// three weight matrices -> f16 in one launch (blockIdx.y selects matrix)
// ---------------------------------------------------------------------------
__global__ __launch_bounds__(256) void f2h3_kernel(const float* __restrict__ a,
                                                   const float* __restrict__ b,
                                                   const float* __restrict__ c,
                                                   unsigned short* __restrict__ oa,
                                                   unsigned short* __restrict__ ob,
                                                   unsigned short* __restrict__ oc,
                                                   int n4) {
  int i = blockIdx.x * 256 + threadIdx.x;
  if (i >= n4) return;
  const float* in = (blockIdx.y == 0) ? a : (blockIdx.y == 1) ? b : c;
  unsigned short* out = (blockIdx.y == 0) ? oa : (blockIdx.y == 1) ? ob : oc;
  float4 v = ((const float4*)in)[i];
  ushort4 o;
  o.x = f2h(v.x); o.y = f2h(v.y); o.z = f2h(v.z); o.w = f2h(v.w);
  ((ushort4*)out)[i] = o;
}

// ---------------------------------------------------------------------------
// 16-bit transpose per batch: in [R][C] -> out [C][R]
// ---------------------------------------------------------------------------
__global__ __launch_bounds__(256) void transpose_h16(const unsigned short* __restrict__ in,
                                                     unsigned short* __restrict__ out,
                                                     int R, int C) {
  __shared__ unsigned short t[32][33];
  const int z = blockIdx.z;
  in  += (long long)z * R * C;
  out += (long long)z * R * C;
  const int c0 = blockIdx.x * 32, r0 = blockIdx.y * 32;
#pragma unroll
  for (int i = 0; i < 4; ++i) {
    int r = threadIdx.y + i * 8;
    t[r][threadIdx.x] = in[(long long)(r0 + r) * C + c0 + threadIdx.x];
  }
  __syncthreads();
#pragma unroll
  for (int i = 0; i < 4; ++i) {
    int r = threadIdx.y + i * 8;
    out[(long long)(c0 + r) * R + r0 + threadIdx.x] = t[threadIdx.x][r];
  }
}

// ---------------------------------------------------------------------------
// f16 MFMA GEMM NT, 8 waves, BN=256, BM = MI*32 (MI=8 -> 256x256, MI=4 ->
// 128x256). BK=32, TRIPLE-buffered LDS, phase-template schedule:
// per phase {issue ds_reads for THIS phase | issue GLDs for tile t+2 into
// buf (t+2)%3 | sched_barrier | s_barrier | lgkmcnt(0) | setprio(1) |
// 16/8 MFMA | setprio(0) | s_barrier}. The reads complete UNDER the barrier
// wait, so lgkmcnt(0) is ~free; counted vmcnt once per tile (never 0 in the
// main loop). Triple buffer => staging never collides with in-flight reads.
// MI=4 declares (512,4): 72KB LDS + <=128 VGPR -> 2 blocks/CU.
// ---------------------------------------------------------------------------
template <int MI, bool OUT_F16>
__global__ __launch_bounds__(512, MI == 4 ? 4 : 2)
void gemm8_nt(const unsigned short* __restrict__ A,
              const unsigned short* __restrict__ B,
              void* __restrict__ Cv,
              int M, int N, int K,
              long long sA, long long sB, long long sC,
              float scale) {
  constexpr int BM  = MI * 32;          // 256 or 128
  constexpr int ASZ = BM * 32;          // u16 per A tile
  constexpr int BSZ = 256 * 32;         // u16 per B tile
  constexpr int TSZ = ASZ + BSZ;        // u16 per buffer
  constexpr int MH  = MI / 2;

  const int bz = blockIdx.z;
  A += (long long)bz * sA;
  B += (long long)bz * sB;

  __shared__ __align__(16) unsigned short lds[3 * TSZ];

  const int tid = threadIdx.x;
  const int lane = tid & 63;
  const int w = tid >> 6;
  const int wr = w >> 2;          // 0..1 : row band
  const int wc = w & 3;           // 0..3 : 64-col band
  const int m0 = blockIdx.y * BM, n0 = blockIdx.x * 256;

  f32x4 acc[MI][4] = {};

  // staging: 512 threads, lane l of wave w -> row tid>>2 (0..127), chunk swizzle
  const int srow = tid >> 2;
  const int scol = ((lane & 3) ^ ((lane >> 3) & 3)) * 8;
  const unsigned short* gA0 = A + (long long)(m0 + srow) * K + scol;
  const unsigned short* gA1 = gA0 + (long long)128 * K;   // MI==8 only
  const unsigned short* gB0 = B + (long long)(n0 + srow) * K + scol;
  const unsigned short* gB1 = gB0 + (long long)128 * K;
  const int wb = w * 512;

  // fragment read offsets (u16 units), same swizzle family as staging
  const int fm = lane & 15;
  const int col8 = ((lane >> 4) ^ ((lane >> 1) & 3)) * 8;
  int aoff[MI], boff[4];
#pragma unroll
  for (int mi = 0; mi < MI; ++mi) aoff[mi] = (wr * (MI * 16) + mi * 16 + fm) * 32 + col8;
#pragma unroll
  for (int ni = 0; ni < 4; ++ni) boff[ni] = ASZ + (wc * 64 + ni * 16 + fm) * 32 + col8;

  const int nt = K >> 5;

  // per-tile GLD order (FIFO for vmcnt): MI=8: A0,A1 | B0,B1 ; MI=4: A0,B0 | B1
#define STAGE_ALL(nb, k0)                                      \
  do {                                                         \
    unsigned short* L_ = lds + (nb) * TSZ;                     \
    if (MI == 8) {                                             \
      GLD16(gA0 + (k0), L_ + wb);                              \
      GLD16(gA1 + (k0), L_ + 4096 + wb);                       \
      GLD16(gB0 + (k0), L_ + ASZ + wb);                        \
      GLD16(gB1 + (k0), L_ + ASZ + 4096 + wb);                 \
    } else {                                                   \
      GLD16(gA0 + (k0), L_ + wb);                              \
      GLD16(gB0 + (k0), L_ + ASZ + wb);                        \
      GLD16(gB1 + (k0), L_ + ASZ + 4096 + wb);                 \
    }                                                          \
  } while (0)

  // prologue: tile0 -> buf0, tile1 -> buf1; wait tile0 landed (tile1 in flight)
  STAGE_ALL(0, 0);
  STAGE_ALL(1, 32);
  if (MI == 8) asm volatile("s_waitcnt vmcnt(4)" ::: "memory");
  else         asm volatile("s_waitcnt vmcnt(3)" ::: "memory");
  __builtin_amdgcn_s_barrier();

  int b0 = 0, b1 = 1, b2 = 2;        // current / next / stage-target
  for (int t = 0; t < nt; ++t) {
    const unsigned short* L = lds + b0 * TSZ;
    unsigned short* Ls = lds + b2 * TSZ;
    const bool st = (t + 2 < nt);
    const int k2 = (t + 2) << 5;

    // ---- phase 0: reads for rows 0..MH-1 + all B; GLD half 1 ----
    f16x8 af[MH], bf[4];
#pragma unroll
    for (int mi = 0; mi < MH; ++mi) af[mi] = *(const f16x8*)(L + aoff[mi]);
#pragma unroll
    for (int ni = 0; ni < 4; ++ni) bf[ni] = *(const f16x8*)(L + boff[ni]);
    if (st) {
      if (MI == 8) { GLD16(gA0 + k2, Ls + wb); GLD16(gA1 + k2, Ls + 4096 + wb); }
      else         { GLD16(gA0 + k2, Ls + wb); GLD16(gB0 + k2, Ls + ASZ + wb); }
    }
    __builtin_amdgcn_sched_barrier(0);
    __builtin_amdgcn_s_barrier();
    asm volatile("s_waitcnt lgkmcnt(0)" ::: "memory");
    __builtin_amdgcn_sched_barrier(0);
    __builtin_amdgcn_s_setprio(1);
#pragma unroll
    for (int mi = 0; mi < MH; ++mi)
#pragma unroll
      for (int ni = 0; ni < 4; ++ni)
        acc[mi][ni] = __builtin_amdgcn_mfma_f32_16x16x32_f16(af[mi], bf[ni],
                                                             acc[mi][ni], 0, 0, 0);
    __builtin_amdgcn_s_setprio(0);
    __builtin_amdgcn_s_barrier();

    // ---- phase 1: reads for rows MH..MI-1; GLD half 2; counted vmcnt ----
    f16x8 ag[MH];
#pragma unroll
    for (int mi = 0; mi < MH; ++mi) ag[mi] = *(const f16x8*)(L + aoff[MH + mi]);
    if (st) {
      if (MI == 8) { GLD16(gB0 + k2, Ls + ASZ + wb); GLD16(gB1 + k2, Ls + ASZ + 4096 + wb); }
      else         { GLD16(gB1 + k2, Ls + ASZ + 4096 + wb); }
    }
    if (st) {
      if (MI == 8) asm volatile("s_waitcnt vmcnt(4)" ::: "memory");
      else         asm volatile("s_waitcnt vmcnt(3)" ::: "memory");
    } else if (t + 1 < nt) {
      asm volatile("s_waitcnt vmcnt(0)" ::: "memory");
    }
    __builtin_amdgcn_sched_barrier(0);
    __builtin_amdgcn_s_barrier();
    asm volatile("s_waitcnt lgkmcnt(0)" ::: "memory");
    __builtin_amdgcn_sched_barrier(0);
    __builtin_amdgcn_s_setprio(1);
#pragma unroll
    for (int mi = 0; mi < MH; ++mi)
#pragma unroll
      for (int ni = 0; ni < 4; ++ni)
        acc[MH + mi][ni] = __builtin_amdgcn_mfma_f32_16x16x32_f16(ag[mi], bf[ni],
                                                                  acc[MH + mi][ni], 0, 0, 0);
    __builtin_amdgcn_s_setprio(0);
    __builtin_amdgcn_s_barrier();

    int tb = b0; b0 = b1; b1 = b2; b2 = tb;
  }
#undef STAGE_ALL

  // epilogue: C/D layout col=lane&15, row=(lane>>4)*4+reg
  const int cm = (lane >> 4) * 4;
  const int cn = lane & 15;
#pragma unroll
  for (int mi = 0; mi < MI; ++mi)
#pragma unroll
    for (int ni = 0; ni < 4; ++ni) {
#pragma unroll
      for (int r = 0; r < 4; ++r) {
        long long m = m0 + wr * (MI * 16) + mi * 16 + cm + r;
        long long n = n0 + wc * 64 + ni * 16 + cn;
        float v = acc[mi][ni][r] * scale;
        if (OUT_F16)
          ((unsigned short*)Cv)[(long long)bz * sC + m * N + n] = f2h(v);
        else
          ((float*)Cv)[(long long)bz * sC + m * N + n] = v;
      }
    }
}

// ---------------------------------------------------------------------------
// Wave-per-2-rows sparsemax/softmax. v6: each wave owns TWO rows — two
// independent 2048-element bitonic networks interleaved for 2x ILP (the
// serial dependence chain of one network hides under the other). No LDS.
// (256,3): VGPR cap ~170 covers r[2][32] + b[2][32] at the swizzle pins.
// ---------------------------------------------------------------------------
template <int K, int J>
__device__ __forceinline__ void intra_s2(float (&r)[2][32]) {
#pragma unroll
  for (int h = 0; h < 2; ++h)
#pragma unroll
    for (int v = 0; v < 32; ++v)
      if ((v & J) == 0) {
        const int u = v | J;
        const bool dsc = ((v & K) == 0);
        float a = r[h][v], b = r[h][u];
        float mx = fmaxf(a, b), mn = fminf(a, b);
        r[h][v] = dsc ? mx : mn;
        r[h][u] = dsc ? mn : mx;
      }
}

template <int J>
__device__ __forceinline__ void intra_desc2(float (&r)[2][32]) {
#pragma unroll
  for (int h = 0; h < 2; ++h)
#pragma unroll
    for (int v = 0; v < 32; ++v)
      if ((v & J) == 0) {
        const int u = v | J;
        float a = r[h][v], b = r[h][u];
        r[h][v] = fmaxf(a, b);
        r[h][u] = fminf(a, b);
      }
}

template <int JL>
__device__ __forceinline__ void cross_desc2(float (&r)[2][32], int lane, int bp32) {
  const bool keepmax = ((lane & JL) == 0);
  float b[2][32];
#pragma unroll
  for (int h = 0; h < 2; ++h)
#pragma unroll
    for (int v = 0; v < 32; ++v) {
      int av = __builtin_bit_cast(int, r[h][v]);
      int bv;
      if constexpr (JL == 32)
        bv = __builtin_amdgcn_ds_bpermute(bp32, av);
      else
        bv = __builtin_amdgcn_ds_swizzle(av, (JL << 10) | 0x1F);  // xor-mode
      b[h][v] = __builtin_bit_cast(float, bv);
    }
  __builtin_amdgcn_sched_barrier(0);   // pin: all 64 swizzles issued before CEs
#pragma unroll
  for (int h = 0; h < 2; ++h)
#pragma unroll
    for (int v = 0; v < 32; ++v) {
      float mx = fmaxf(r[h][v], b[h][v]), mn = fminf(r[h][v], b[h][v]);
      r[h][v] = keepmax ? mx : mn;
    }
}

__device__ __forceinline__ void signfix2(float (&r)[2][32], unsigned fix) {
#pragma unroll
  for (int h = 0; h < 2; ++h)
#pragma unroll
    for (int v = 0; v < 32; ++v)
      r[h][v] = __builtin_bit_cast(float, __builtin_bit_cast(unsigned, r[h][v]) ^ fix);
}

__global__ __launch_bounds__(256, 3) void attn_row_wave(const float* __restrict__ scores,
                                                        unsigned short* __restrict__ attn,
                                                        const float* __restrict__ absSum) {
  const int tid = threadIdx.x;
  const int lane = tid & 63;
  const int rbase = blockIdx.x * 8 + (tid >> 6) * 2;
  const float* rowp = scores + (long long)rbase * NROW;
  unsigned short* aout = attn + (long long)rbase * NROW;
  const int bp32 = (lane ^ 32) << 2;

  float r[2][32];
  float lm[2] = {-INFINITY, -INFINITY};
  float ls[2] = {0.f, 0.f};
#pragma unroll
  for (int h = 0; h < 2; ++h) {
    const float4* rp4 = (const float4*)(rowp + h * NROW) + lane * 8;
#pragma unroll
    for (int q = 0; q < 8; ++q) {
      float4 v = rp4[q];
      r[h][q * 4 + 0] = v.x; r[h][q * 4 + 1] = v.y;
      r[h][q * 4 + 2] = v.z; r[h][q * 4 + 3] = v.w;
      lm[h] = fmaxf(lm[h], fmaxf(fmaxf(v.x, v.y), fmaxf(v.z, v.w)));
      ls[h] += v.x + v.y + v.z + v.w;
    }
  }
#pragma unroll
  for (int off = 32; off; off >>= 1) {
#pragma unroll
    for (int h = 0; h < 2; ++h) {
      lm[h] = fmaxf(lm[h], __shfl_xor(lm[h], off, 64));
      ls[h] += __shfl_xor(ls[h], off, 64);
    }
  }

  const bool use_softmax = (absSum[0] * (1.0f / TOTX)) >= 1.0f;

  if (use_softmax) {
    float sum[2] = {0.f, 0.f};
#pragma unroll
    for (int h = 0; h < 2; ++h)
#pragma unroll
      for (int v = 0; v < 32; ++v) { r[h][v] = expf(r[h][v] - lm[h]); sum[h] += r[h][v]; }
#pragma unroll
    for (int off = 32; off; off >>= 1)
#pragma unroll
      for (int h = 0; h < 2; ++h) sum[h] += __shfl_xor(sum[h], off, 64);
#pragma unroll
    for (int h = 0; h < 2; ++h) {
      float inv = 1.0f / sum[h];
      ushort4* op = (ushort4*)(aout + h * NROW + lane * 32);
#pragma unroll
      for (int q = 0; q < 8; ++q) {
        ushort4 o;
        o.x = f2h(r[h][q * 4 + 0] * inv); o.y = f2h(r[h][q * 4 + 1] * inv);
        o.z = f2h(r[h][q * 4 + 2] * inv); o.w = f2h(r[h][q * 4 + 3] * inv);
        op[q] = o;
      }
    }
    return;
  }

  // ---- sparsemax (two rows interleaved) ----
  float step[2];
#pragma unroll
  for (int h = 0; h < 2; ++h) {
#pragma unroll
    for (int v = 0; v < 32; ++v) r[h][v] -= lm[h];
    step[h] = ((ls[h] - (float)NROW * lm[h]) - 1.0f) * (1.0f / (float)NROW);
  }

  // per-lane bitonic presort (compile-time directions)
  intra_s2<2, 1>(r);
  intra_s2<4, 2>(r); intra_s2<4, 1>(r);
  intra_s2<8, 4>(r); intra_s2<8, 2>(r); intra_s2<8, 1>(r);
  intra_s2<16, 8>(r); intra_s2<16, 4>(r); intra_s2<16, 2>(r); intra_s2<16, 1>(r);

  // merge ladder with running sign mask (negate-on-!dsc => all merges desc)
  unsigned cur = (unsigned)(lane & 1) << 31;               // kl=1
  signfix2(r, cur);
  intra_desc2<16>(r); intra_desc2<8>(r); intra_desc2<4>(r);
  intra_desc2<2>(r); intra_desc2<1>(r);

  { unsigned want = (unsigned)(lane & 2) << 30;            // kl=2
    signfix2(r, cur ^ want); cur = want; }
  cross_desc2<1>(r, lane, bp32);
  intra_desc2<16>(r); intra_desc2<8>(r); intra_desc2<4>(r);
  intra_desc2<2>(r); intra_desc2<1>(r);

  { unsigned want = (unsigned)(lane & 4) << 29;            // kl=4
    signfix2(r, cur ^ want); cur = want; }
  cross_desc2<2>(r, lane, bp32); cross_desc2<1>(r, lane, bp32);
  intra_desc2<16>(r); intra_desc2<8>(r); intra_desc2<4>(r);
  intra_desc2<2>(r); intra_desc2<1>(r);

  { unsigned want = (unsigned)(lane & 8) << 28;            // kl=8
    signfix2(r, cur ^ want); cur = want; }
  cross_desc2<4>(r, lane, bp32); cross_desc2<2>(r, lane, bp32);
  cross_desc2<1>(r, lane, bp32);
  intra_desc2<16>(r); intra_desc2<8>(r); intra_desc2<4>(r);
  intra_desc2<2>(r); intra_desc2<1>(r);

  { unsigned want = (unsigned)(lane & 16) << 27;           // kl=16
    signfix2(r, cur ^ want); cur = want; }
  cross_desc2<8>(r, lane, bp32); cross_desc2<4>(r, lane, bp32);
  cross_desc2<2>(r, lane, bp32); cross_desc2<1>(r, lane, bp32);
  intra_desc2<16>(r); intra_desc2<8>(r); intra_desc2<4>(r);
  intra_desc2<2>(r); intra_desc2<1>(r);

  { unsigned want = (unsigned)(lane & 32) << 26;           // kl=32
    signfix2(r, cur ^ want); cur = want; }
  cross_desc2<16>(r, lane, bp32); cross_desc2<8>(r, lane, bp32);
  cross_desc2<4>(r, lane, bp32); cross_desc2<2>(r, lane, bp32);
  cross_desc2<1>(r, lane, bp32);
  intra_desc2<16>(r); intra_desc2<8>(r); intra_desc2<4>(r);
  intra_desc2<2>(r); intra_desc2<1>(r);

  signfix2(r, cur);                                        // kl=64: dsc true
  cross_desc2<32>(r, lane, bp32); cross_desc2<16>(r, lane, bp32);
  cross_desc2<8>(r, lane, bp32); cross_desc2<4>(r, lane, bp32);
  cross_desc2<2>(r, lane, bp32); cross_desc2<1>(r, lane, bp32);
  intra_desc2<16>(r); intra_desc2<8>(r); intra_desc2<4>(r);
  intra_desc2<2>(r); intra_desc2<1>(r);

  // k = count(sorted > step), per row
  float kf[2];
#pragma unroll
  for (int h = 0; h < 2; ++h) {
    float lcnt = 0.f;
#pragma unroll
    for (int v = 0; v < 32; ++v) lcnt += (r[h][v] > step[h]) ? 1.0f : 0.0f;
#pragma unroll
    for (int off = 32; off; off >>= 1) lcnt += __shfl_xor(lcnt, off, 64);
    kf[h] = lcnt;
  }

  // inclusive cumsum: local sequential + wave scan of lane totals, per row
#pragma unroll
  for (int h = 0; h < 2; ++h) {
    float run = 0.f;
#pragma unroll
    for (int v = 0; v < 32; ++v) { run += r[h][v]; r[h][v] = run; }
    float pre = run;
#pragma unroll
    for (int off = 1; off < 64; off <<= 1) {
      float t = __shfl_up(pre, off, 64);
      if (lane >= off) pre += t;
    }
    pre -= run;
#pragma unroll
    for (int v = 0; v < 32; ++v) r[h][v] += pre;
  }

  // epilogue: re-read original z through a laundered pointer (blocks CSE)
  unsigned long long up = (unsigned long long)rowp;
  asm volatile("" : "+v"(up));
#pragma unroll
  for (int h = 0; h < 2; ++h) {
    const float inv_k = 1.0f / kf[h];
    const float c1 = 1.0f + step[h] * kf[h];
    const float4* rp4e = (const float4*)(up + (unsigned long long)h * NROW * 4) + lane * 8;
    ushort4* op = (ushort4*)(aout + h * NROW + lane * 32);
#pragma unroll
    for (int q = 0; q < 8; ++q) {
      float4 v = rp4e[q];
      ushort4 o;
      o.x = f2h(fmaxf((v.x - lm[h]) - (r[h][q * 4 + 0] - c1) * inv_k, 0.0f));
      o.y = f2h(fmaxf((v.y - lm[h]) - (r[h][q * 4 + 1] - c1) * inv_k, 0.0f));
      o.z = f2h(fmaxf((v.z - lm[h]) - (r[h][q * 4 + 2] - c1) * inv_k, 0.0f));
      o.w = f2h(fmaxf((v.w - lm[h]) - (r[h][q * 4 + 3] - c1) * inv_k, 0.0f));
      op[q] = o;
    }
  }
}

// ---------------------------------------------------------------------------
extern "C" void kernel_launch(void* const* d_in, const int* in_sizes, int n_in,
                              void* d_out, int out_size, void* d_ws, size_t ws_size,
                              hipStream_t stream) {
  const float* x  = (const float*)d_in[0];
  const float* Wq = (const float*)d_in[1];
  const float* Wk = (const float*)d_in[2];
  const float* Wv = (const float*)d_in[3];
  float* out = (float*)d_out;

  const long long NX = (long long)B_ * S_ * D_;   // 8M
  const long long NW = (long long)H_ * D_;        // 1M

  // Workspace layout (total 144 MB + 4 B):
  //  [0,16MB):    x16          -> later Sc (fp32, 64MB, overwrites x16+W)
  //  [16,22MB):   Wq16 Wk16 Wv16 (contiguous, 2MB apart -> fused proj)
  //  [64,80MB):   Vt16 (persists to PV)
  //  [80,96MB):   Q16   [96,112MB): K16   [112,128MB): V16
  //  [80,112MB):  A16 (f16 attention, 32MB; overwrites Q16/K16 after scores)
  //  [144MB]:     flag
  char* base = (char*)d_ws;
  unsigned short* x16  = (unsigned short*)(base);
  unsigned short* Wq16 = (unsigned short*)(base + (16ll << 20));
  unsigned short* Wk16 = (unsigned short*)(base + (18ll << 20));
  unsigned short* Wv16 = (unsigned short*)(base + (20ll << 20));
  float*          Sc   = (float*)(base);
  unsigned short* Vt16 = (unsigned short*)(base + (64ll << 20));
  unsigned short* Q16  = (unsigned short*)(base + (80ll << 20));
  unsigned short* K16  = (unsigned short*)(base + (96ll << 20));
  unsigned short* V16  = (unsigned short*)(base + (112ll << 20));
  unsigned short* A16  = (unsigned short*)(base + (80ll << 20));
  float*          flag = (float*)(base + (144ll << 20));

  hipMemsetAsync(flag, 0, sizeof(float), stream);

  // fused x->f16 + abs-sum (grid-stride)
  f2h_abs_kernel<<<1024, 256, 0, stream>>>(x, x16, flag, (int)(NX / 4));
  // W -> f16, one launch
  f2h3_kernel<<<dim3((int)(NW / 4 + 255) / 256, 3), 256, 0, stream>>>(
      Wq, Wk, Wv, Wq16, Wk16, Wv16, (int)(NW / 4));

  // Projections fused: z selects W (stride 1M elems) and output (stride 8M elems)
  // MI=4 (128x256): 4 x 64 x 3 = 768 blocks, 2 blocks/CU -> 1.5 dense rounds
  {
    dim3 grid(H_ / 256, (B_ * S_) / 128, 3);
    gemm8_nt<4, true><<<grid, 512, 0, stream>>>(x16, Wq16, Q16, B_ * S_, H_, D_,
                                                0, (long long)NW, (long long)(8ll << 20),
                                                1.0f);
  }

  // V^T per batch: [S][H] -> [H][S]
  {
    dim3 grid(H_ / 32, S_ / 32, B_);
    transpose_h16<<<grid, dim3(32, 8), 0, stream>>>(V16, Vt16, S_, H_);
  }

  // scores = Q @ K^T / 32 (batched, fp32 out; overwrites x16/W — all dead)
  // MI=8 (256x256): 8 x 8 x 4 = 256 blocks = 1/CU
  {
    dim3 grid(S_ / 256, S_ / 256, B_);
    gemm8_nt<8, false><<<grid, 512, 0, stream>>>(Q16, K16, Sc, S_, S_, H_,
                                                 (long long)S_ * H_, (long long)S_ * H_,
                                                 (long long)S_ * S_, 1.0f / 32.0f);
  }

  // attention = sparsemax-or-softmax(scores) -> f16 (one wave per 2 rows)
  attn_row_wave<<<(B_ * S_) / 8, 256, 0, stream>>>(Sc, A16, flag);

  // out = attention @ Vt^T, f16 MFMA, fp32 out
  // MI=4 (128x256): 4 x 16 x 4 = 256 blocks, 2 blocks/CU
  {
    dim3 grid(H_ / 256, S_ / 128, B_);
    gemm8_nt<4, false><<<grid, 512, 0, stream>>>(A16, Vt16, out, S_, H_, S_,
                                                 (long long)S_ * S_, (long long)H_ * S_,
                                                 (long long)S_ * H_, 1.0f);
  }
}

// Round 5
// 354.237 us; speedup vs baseline: 1.0312x; 1.0312x over previous
//
#include <hip/hip_runtime.h>
#include <math.h>

// Problem constants
#define B_   4
#define S_   2048
#define D_   1024
#define H_   1024
#define NROW 2048
#define TOTX 8388608.0f            // B_*S_*D_ elements of x

typedef _Float16 f16x8 __attribute__((ext_vector_type(8)));
typedef float f32x4 __attribute__((ext_vector_type(4)));
typedef unsigned short us8 __attribute__((ext_vector_type(8)));

__device__ __forceinline__ unsigned short f2h(float f) {
  _Float16 h = (_Float16)f;                       // v_cvt_f16_f32, RNE
  return __builtin_bit_cast(unsigned short, h);
}

// async global->LDS, 16B per lane, lands at ldsbase + lane*16
#define GLD16(gp, lp)                                                            \
  __builtin_amdgcn_global_load_lds(                                              \
      (__attribute__((address_space(1))) void*)(gp),                             \
      (__attribute__((address_space(3))) void*)(lp), 16, 0, 0)

// ---------------------------------------------------------------------------
// fused float->f16 conversion + abs-sum for x (one pass over 32 MB)
// ---------------------------------------------------------------------------
__global__ __launch_bounds__(256) void f2h_abs_kernel(const float* __restrict__ in,
                                                      unsigned short* __restrict__ out,
                                                      float* absOut, int n4) {
  int i0 = blockIdx.x * 256 + threadIdx.x;
  int stride = gridDim.x * 256;
  float s = 0.f;
  for (int i = i0; i < n4; i += stride) {
    float4 v = ((const float4*)in)[i];
    ushort4 o;
    o.x = f2h(v.x); o.y = f2h(v.y); o.z = f2h(v.z); o.w = f2h(v.w);
    ((ushort4*)out)[i] = o;
    s += fabsf(v.x) + fabsf(v.y) + fabsf(v.z) + fabsf(v.w);
  }
#pragma unroll
  for (int off = 32; off; off >>= 1) s += __shfl_xor(s, off);
  __shared__ float red[4];
  if ((threadIdx.x & 63) == 0) red[threadIdx.x >> 6] = s;
  __syncthreads();
  if (threadIdx.x == 0) atomicAdd(absOut, red[0] + red[1] + red[2] + red[3]);
}

// ---------------------------------------------------------------------------
// three weight matrices -> f16 in one launch (blockIdx.y selects matrix)
// ---------------------------------------------------------------------------
__global__ __launch_bounds__(256) void f2h3_kernel(const float* __restrict__ a,
                                                   const float* __restrict__ b,
                                                   const float* __restrict__ c,
                                                   unsigned short* __restrict__ oa,
                                                   unsigned short* __restrict__ ob,
                                                   unsigned short* __restrict__ oc,
                                                   int n4) {
  int i = blockIdx.x * 256 + threadIdx.x;
  if (i >= n4) return;
  const float* in = (blockIdx.y == 0) ? a : (blockIdx.y == 1) ? b : c;
  unsigned short* out = (blockIdx.y == 0) ? oa : (blockIdx.y == 1) ? ob : oc;
  float4 v = ((const float4*)in)[i];
  ushort4 o;
  o.x = f2h(v.x); o.y = f2h(v.y); o.z = f2h(v.z); o.w = f2h(v.w);
  ((ushort4*)out)[i] = o;
}

// ---------------------------------------------------------------------------
// 16-bit transpose per batch: in [R][C] -> out [C][R]
// ---------------------------------------------------------------------------
__global__ __launch_bounds__(256) void transpose_h16(const unsigned short* __restrict__ in,
                                                     unsigned short* __restrict__ out,
                                                     int R, int C) {
  __shared__ unsigned short t[32][33];
  const int z = blockIdx.z;
  in  += (long long)z * R * C;
  out += (long long)z * R * C;
  const int c0 = blockIdx.x * 32, r0 = blockIdx.y * 32;
#pragma unroll
  for (int i = 0; i < 4; ++i) {
    int r = threadIdx.y + i * 8;
    t[r][threadIdx.x] = in[(long long)(r0 + r) * C + c0 + threadIdx.x];
  }
  __syncthreads();
#pragma unroll
  for (int i = 0; i < 4; ++i) {
    int r = threadIdx.y + i * 8;
    out[(long long)(c0 + r) * R + r0 + threadIdx.x] = t[threadIdx.x][r];
  }
}

// ---------------------------------------------------------------------------
// f16 MFMA GEMM NT (round-3 version, known good), 8 waves, BN=256,
// BM = MI*32. BK=32, double-buffered LDS with COUNTED vmcnt: tile t+2 is
// staged into the buffer t just vacated (after a read-done barrier), and the
// end-of-iter wait is vmcnt(NLD) -- never 0 in the main loop. 2 barriers/tile.
// ---------------------------------------------------------------------------
template <int MI, bool OUT_F16>
__global__ __launch_bounds__(512, 2) void gemm8_nt(const unsigned short* __restrict__ A,
                                                   const unsigned short* __restrict__ B,
                                                   void* __restrict__ Cv,
                                                   int M, int N, int K,
                                                   long long sA, long long sB, long long sC,
                                                   float scale) {
  constexpr int BM  = MI * 32;          // 256 or 128
  constexpr int ASZ = BM * 32;          // u16 per A tile
  constexpr int BSZ = 256 * 32;         // u16 per B tile
  constexpr int TSZ = ASZ + BSZ;        // u16 per buffer
  constexpr int MH  = MI / 2;           // frags per phase-half

  const int bz = blockIdx.z;
  A += (long long)bz * sA;
  B += (long long)bz * sB;

  __shared__ __align__(16) unsigned short lds[2 * TSZ];

  const int tid = threadIdx.x;
  const int lane = tid & 63;
  const int w = tid >> 6;
  const int wr = w >> 2;          // 0..1 : row band (BM/2 rows)
  const int wc = w & 3;           // 0..3 : 64-col band
  const int m0 = blockIdx.y * BM, n0 = blockIdx.x * 256;

  f32x4 acc[MI][4] = {};

  // staging: 512 threads, lane l of wave w -> row tid>>2 (0..127), chunk swizzle
  const int srow = tid >> 2;
  const int scol = ((lane & 3) ^ ((lane >> 3) & 3)) * 8;
  const unsigned short* gA0 = A + (long long)(m0 + srow) * K + scol;
  const unsigned short* gA1 = gA0 + (long long)128 * K;   // MI==8 only
  const unsigned short* gB0 = B + (long long)(n0 + srow) * K + scol;
  const unsigned short* gB1 = gB0 + (long long)128 * K;
  const int wb = w * 512;

  // fragment read offsets (u16 units), same swizzle family as staging
  const int fm = lane & 15;
  const int col8 = ((lane >> 4) ^ ((lane >> 1) & 3)) * 8;
  int aoff[MI], boff[4];
#pragma unroll
  for (int mi = 0; mi < MI; ++mi) aoff[mi] = (wr * (MI * 16) + mi * 16 + fm) * 32 + col8;
#pragma unroll
  for (int ni = 0; ni < 4; ++ni) boff[ni] = ASZ + (wc * 64 + ni * 16 + fm) * 32 + col8;

  const int nt = K >> 5;

#define STAGE(nb, k0)                                    \
  do {                                                   \
    unsigned short* L_ = lds + (nb) * TSZ;               \
    GLD16(gA0 + (k0), L_ + wb);                          \
    if (MI == 8) GLD16(gA1 + (k0), L_ + 4096 + wb);      \
    GLD16(gB0 + (k0), L_ + ASZ + wb);                    \
    GLD16(gB1 + (k0), L_ + ASZ + 4096 + wb);             \
  } while (0)

  // prologue: stage tiles 0 and 1 (K >= 64 always here)
  STAGE(0, 0);
  STAGE(1, 32);
  if (MI == 8) asm volatile("s_waitcnt vmcnt(4)" ::: "memory");
  else         asm volatile("s_waitcnt vmcnt(3)" ::: "memory");
  __builtin_amdgcn_s_barrier();

  for (int t = 0; t < nt; ++t) {
    const unsigned short* L = lds + (t & 1) * TSZ;
    // half 1: A-lo frags + all B frags, 4*MH MFMAs
    f16x8 af[MH], bf[4];
#pragma unroll
    for (int mi = 0; mi < MH; ++mi) af[mi] = *(const f16x8*)(L + aoff[mi]);
#pragma unroll
    for (int ni = 0; ni < 4; ++ni) bf[ni] = *(const f16x8*)(L + boff[ni]);
    __builtin_amdgcn_s_setprio(1);
#pragma unroll
    for (int mi = 0; mi < MH; ++mi)
#pragma unroll
      for (int ni = 0; ni < 4; ++ni)
        acc[mi][ni] = __builtin_amdgcn_mfma_f32_16x16x32_f16(af[mi], bf[ni],
                                                             acc[mi][ni], 0, 0, 0);
    __builtin_amdgcn_s_setprio(0);
    // half 2 reads, then declare this buffer fully read (barrier)
    f16x8 ag[MH];
#pragma unroll
    for (int mi = 0; mi < MH; ++mi) ag[mi] = *(const f16x8*)(L + aoff[MH + mi]);
    asm volatile("s_waitcnt lgkmcnt(0)" ::: "memory");
    __builtin_amdgcn_sched_barrier(0);
    __builtin_amdgcn_s_barrier();
    // refill the vacated buffer with tile t+2 while computing half 2
    if (t + 2 < nt) STAGE(t & 1, (t + 2) << 5);
    __builtin_amdgcn_s_setprio(1);
#pragma unroll
    for (int mi = 0; mi < MH; ++mi)
#pragma unroll
      for (int ni = 0; ni < 4; ++ni)
        acc[MH + mi][ni] = __builtin_amdgcn_mfma_f32_16x16x32_f16(ag[mi], bf[ni],
                                                                  acc[MH + mi][ni], 0, 0, 0);
    __builtin_amdgcn_s_setprio(0);
    // counted wait: tile t+1 landed, t+2's loads stay in flight
    if (t + 2 < nt) {
      if (MI == 8) asm volatile("s_waitcnt vmcnt(4)" ::: "memory");
      else         asm volatile("s_waitcnt vmcnt(3)" ::: "memory");
    } else if (t + 1 < nt) {
      asm volatile("s_waitcnt vmcnt(0)" ::: "memory");
    }
    __builtin_amdgcn_s_barrier();
  }
#undef STAGE

  // epilogue: C/D layout col=lane&15, row=(lane>>4)*4+reg
  const int cm = (lane >> 4) * 4;
  const int cn = lane & 15;
#pragma unroll
  for (int mi = 0; mi < MI; ++mi)
#pragma unroll
    for (int ni = 0; ni < 4; ++ni) {
#pragma unroll
      for (int r = 0; r < 4; ++r) {
        long long m = m0 + wr * (MI * 16) + mi * 16 + cm + r;
        long long n = n0 + wc * 64 + ni * 16 + cn;
        float v = acc[mi][ni][r] * scale;
        if (OUT_F16)
          ((unsigned short*)Cv)[(long long)bz * sC + m * N + n] = f2h(v);
        else
          ((float*)Cv)[(long long)bz * sC + m * N + n] = v;
      }
    }
}

// ---------------------------------------------------------------------------
// BLOCK-per-row sparsemax/softmax. v7: 256 threads (4 waves) per row, 8
// elements/thread, e = tid*8 + v. The bitonic network's per-thread serial
// chain shrinks 4x vs wave-per-row (66 stages x 4 CE-pairs instead of x16)
// and the grid grows to 8192 blocks -> full TLP. Exchanges:
//   J=1,2,4   : intra-thread (compile-time)
//   J=8..128  : ds_swizzle lane^(J/8)        (xor masks 1..16)
//   J=256     : ds_bpermute lane^32
//   J=512,1024: LDS round-trip (wave^(J/512)), lane-contiguous 16B accesses
// Sign-flip trick unchanged: level-kl direction bit e&kl is a tid bit for
// kl>=8 (uniform per thread); exchange partners always share sign state
// because exchange distance J < kl. Bit-exact vs v5's network.
// ---------------------------------------------------------------------------
template <int K, int J>
__device__ __forceinline__ void p_intra_s(float (&r)[8]) {
#pragma unroll
  for (int v = 0; v < 8; ++v)
    if ((v & J) == 0) {
      const int u = v | J;
      const bool dsc = ((v & K) == 0);
      float a = r[v], b = r[u];
      float mx = fmaxf(a, b), mn = fminf(a, b);
      r[v] = dsc ? mx : mn;
      r[u] = dsc ? mn : mx;
    }
}

template <int J>
__device__ __forceinline__ void p_intra_d(float (&r)[8]) {
#pragma unroll
  for (int v = 0; v < 8; ++v)
    if ((v & J) == 0) {
      const int u = v | J;
      float a = r[v], b = r[u];
      r[v] = fmaxf(a, b);
      r[u] = fminf(a, b);
    }
}

// cross-lane descending CE; LJ = lane xor distance (elem J / 8)
template <int LJ>
__device__ __forceinline__ void p_cross_d(float (&r)[8], int lane, int bp32) {
  const bool keepmax = ((lane & LJ) == 0);
  float b[8];
#pragma unroll
  for (int v = 0; v < 8; ++v) {
    int av = __builtin_bit_cast(int, r[v]);
    int bv;
    if constexpr (LJ == 32)
      bv = __builtin_amdgcn_ds_bpermute(bp32, av);
    else
      bv = __builtin_amdgcn_ds_swizzle(av, (LJ << 10) | 0x1F);  // xor-mode
    b[v] = __builtin_bit_cast(float, bv);
  }
  __builtin_amdgcn_sched_barrier(0);
#pragma unroll
  for (int v = 0; v < 8; ++v) {
    float mx = fmaxf(r[v], b[v]), mn = fminf(r[v], b[v]);
    r[v] = keepmax ? mx : mn;
  }
}

// cross-wave descending CE via LDS; WJ = wave xor distance (1 or 2)
__device__ __forceinline__ void p_lds_d(float (&r)[8], float* LB, int tid, int wv, int WJ) {
  const bool keepmax = ((wv & WJ) == 0);
  __syncthreads();                       // LB free (prior reads done)
  float4* my = (float4*)(LB + tid * 8);
  my[0] = make_float4(r[0], r[1], r[2], r[3]);
  my[1] = make_float4(r[4], r[5], r[6], r[7]);
  __syncthreads();
  const float4* pp = (const float4*)(LB + (tid ^ (WJ << 6)) * 8);
  float4 p0 = pp[0], p1 = pp[1];
  float p[8] = {p0.x, p0.y, p0.z, p0.w, p1.x, p1.y, p1.z, p1.w};
#pragma unroll
  for (int v = 0; v < 8; ++v) {
    float mx = fmaxf(r[v], p[v]), mn = fminf(r[v], p[v]);
    r[v] = keepmax ? mx : mn;
  }
}

__device__ __forceinline__ void sf8(float (&r)[8], unsigned fix) {
#pragma unroll
  for (int v = 0; v < 8; ++v)
    r[v] = __builtin_bit_cast(float, __builtin_bit_cast(unsigned, r[v]) ^ fix);
}

__global__ __launch_bounds__(256, 6) void attn_row_wave(const float* __restrict__ scores,
                                                        unsigned short* __restrict__ attn,
                                                        const float* __restrict__ absSum) {
  __shared__ float LB[2048];             // 8 KB exchange buffer
  __shared__ float red[8];
  const int tid = threadIdx.x;
  const int lane = tid & 63;
  const int wv = tid >> 6;
  const int row = blockIdx.x;
  const float* rowp = scores + (long long)row * NROW;
  unsigned short* aout = attn + (long long)row * NROW;
  const int bp32 = (lane ^ 32) << 2;

  // load 8 contiguous elems (two float4) at e = tid*8
  const float4* rp4 = (const float4*)rowp + tid * 2;
  float4 v0 = rp4[0], v1 = rp4[1];
  float r[8] = {v0.x, v0.y, v0.z, v0.w, v1.x, v1.y, v1.z, v1.w};

  // block-wide max & raw sum
  float lm = fmaxf(fmaxf(fmaxf(r[0], r[1]), fmaxf(r[2], r[3])),
                   fmaxf(fmaxf(r[4], r[5]), fmaxf(r[6], r[7])));
  float ls = r[0] + r[1] + r[2] + r[3] + r[4] + r[5] + r[6] + r[7];
#pragma unroll
  for (int off = 32; off; off >>= 1) {
    lm = fmaxf(lm, __shfl_xor(lm, off, 64));
    ls += __shfl_xor(ls, off, 64);
  }
  if (lane == 0) { red[wv] = lm; red[4 + wv] = ls; }
  __syncthreads();
  lm = fmaxf(fmaxf(red[0], red[1]), fmaxf(red[2], red[3]));
  ls = red[4] + red[5] + red[6] + red[7];

  const bool use_softmax = (absSum[0] * (1.0f / TOTX)) >= 1.0f;

  if (use_softmax) {
    float s = 0.f;
#pragma unroll
    for (int v = 0; v < 8; ++v) { r[v] = expf(r[v] - lm); s += r[v]; }
#pragma unroll
    for (int off = 32; off; off >>= 1) s += __shfl_xor(s, off, 64);
    __syncthreads();                   // red free
    if (lane == 0) red[wv] = s;
    __syncthreads();
    float inv = 1.0f / (red[0] + red[1] + red[2] + red[3]);
    us8 o;
#pragma unroll
    for (int v = 0; v < 8; ++v) o[v] = f2h(r[v] * inv);
    *(us8*)(aout + tid * 8) = o;
    return;
  }

  // ---- sparsemax ----
#pragma unroll
  for (int v = 0; v < 8; ++v) r[v] -= lm;
  const float step = ((ls - (float)NROW * lm) - 1.0f) * (1.0f / (float)NROW);

  // presort kl=2,4 (compile-time directions on v bits)
  p_intra_s<2, 1>(r);
  p_intra_s<4, 2>(r); p_intra_s<4, 1>(r);

  unsigned cur;
  // kl=8 (dir bit: tid&1)
  cur = (tid & 1) ? 0x80000000u : 0u; sf8(r, cur);
  p_intra_d<4>(r); p_intra_d<2>(r); p_intra_d<1>(r);
  // kl=16 (tid&2): J=8
  { unsigned want = (tid & 2) ? 0x80000000u : 0u; sf8(r, cur ^ want); cur = want; }
  p_cross_d<1>(r, lane, bp32);
  p_intra_d<4>(r); p_intra_d<2>(r); p_intra_d<1>(r);
  // kl=32 (tid&4): J=16,8
  { unsigned want = (tid & 4) ? 0x80000000u : 0u; sf8(r, cur ^ want); cur = want; }
  p_cross_d<2>(r, lane, bp32); p_cross_d<1>(r, lane, bp32);
  p_intra_d<4>(r); p_intra_d<2>(r); p_intra_d<1>(r);
  // kl=64 (tid&8): J=32,16,8
  { unsigned want = (tid & 8) ? 0x80000000u : 0u; sf8(r, cur ^ want); cur = want; }
  p_cross_d<4>(r, lane, bp32); p_cross_d<2>(r, lane, bp32); p_cross_d<1>(r, lane, bp32);
  p_intra_d<4>(r); p_intra_d<2>(r); p_intra_d<1>(r);
  // kl=128 (tid&16): J=64..8
  { unsigned want = (tid & 16) ? 0x80000000u : 0u; sf8(r, cur ^ want); cur = want; }
  p_cross_d<8>(r, lane, bp32); p_cross_d<4>(r, lane, bp32);
  p_cross_d<2>(r, lane, bp32); p_cross_d<1>(r, lane, bp32);
  p_intra_d<4>(r); p_intra_d<2>(r); p_intra_d<1>(r);
  // kl=256 (tid&32): J=128..8
  { unsigned want = (tid & 32) ? 0x80000000u : 0u; sf8(r, cur ^ want); cur = want; }
  p_cross_d<16>(r, lane, bp32); p_cross_d<8>(r, lane, bp32); p_cross_d<4>(r, lane, bp32);
  p_cross_d<2>(r, lane, bp32); p_cross_d<1>(r, lane, bp32);
  p_intra_d<4>(r); p_intra_d<2>(r); p_intra_d<1>(r);
  // kl=512 (tid&64): J=256..8
  { unsigned want = (tid & 64) ? 0x80000000u : 0u; sf8(r, cur ^ want); cur = want; }
  p_cross_d<32>(r, lane, bp32); p_cross_d<16>(r, lane, bp32); p_cross_d<8>(r, lane, bp32);
  p_cross_d<4>(r, lane, bp32); p_cross_d<2>(r, lane, bp32); p_cross_d<1>(r, lane, bp32);
  p_intra_d<4>(r); p_intra_d<2>(r); p_intra_d<1>(r);
  // kl=1024 (tid&128): J=512(LDS),256..8
  { unsigned want = (tid & 128) ? 0x80000000u : 0u; sf8(r, cur ^ want); cur = want; }
  p_lds_d(r, LB, tid, wv, 1);
  p_cross_d<32>(r, lane, bp32); p_cross_d<16>(r, lane, bp32); p_cross_d<8>(r, lane, bp32);
  p_cross_d<4>(r, lane, bp32); p_cross_d<2>(r, lane, bp32); p_cross_d<1>(r, lane, bp32);
  p_intra_d<4>(r); p_intra_d<2>(r); p_intra_d<1>(r);
  // kl=2048 (dir bit always 0 -> desc): J=1024(LDS),512(LDS),256..8
  sf8(r, cur); cur = 0;
  p_lds_d(r, LB, tid, wv, 2);
  p_lds_d(r, LB, tid, wv, 1);
  p_cross_d<32>(r, lane, bp32); p_cross_d<16>(r, lane, bp32); p_cross_d<8>(r, lane, bp32);
  p_cross_d<4>(r, lane, bp32); p_cross_d<2>(r, lane, bp32); p_cross_d<1>(r, lane, bp32);
  p_intra_d<4>(r); p_intra_d<2>(r); p_intra_d<1>(r);
  // r now holds the descending-sorted row, position e = tid*8 + v

  // k = count(sorted > step); cumsum: thread-local + wave scan + wave offsets
  float lcnt = 0.f;
#pragma unroll
  for (int v = 0; v < 8; ++v) lcnt += (r[v] > step) ? 1.0f : 0.0f;
#pragma unroll
  for (int off = 32; off; off >>= 1) lcnt += __shfl_xor(lcnt, off, 64);

  float run = 0.f;
#pragma unroll
  for (int v = 0; v < 8; ++v) { run += r[v]; r[v] = run; }
  float sc = run;
#pragma unroll
  for (int off = 1; off < 64; off <<= 1) {
    float t = __shfl_up(sc, off, 64);
    if (lane >= off) sc += t;
  }
  const float tex = sc - run;            // exclusive prefix within wave

  __syncthreads();                       // red + LB free
  if (lane == 0)  red[wv] = lcnt;        // wave-reduced count (same in all lanes)
  if (lane == 63) red[4 + wv] = sc;      // wave total
  __syncthreads();
  const float kf = red[0];               // all four wave counts are the full row count? no:
  // NOTE: lcnt was reduced per wave only -> sum the four wave counts:
  const float kfull = red[0] + red[1] + red[2] + red[3];
  (void)kf;
  float wex = 0.f;
  if (wv > 0) wex += red[4];
  if (wv > 1) wex += red[5];
  if (wv > 2) wex += red[6];
#pragma unroll
  for (int v = 0; v < 8; ++v) r[v] += tex + wex;

  const float inv_k = 1.0f / kfull;
  const float c1 = 1.0f + step * kfull;

  // epilogue: re-read original z through a laundered pointer (blocks CSE of
  // the first-pass loads across the whole sort -> no extra live range)
  unsigned long long up = (unsigned long long)rowp;
  asm volatile("" : "+v"(up));
  const float4* rp4e = (const float4*)up + tid * 2;
  float4 w0 = rp4e[0], w1 = rp4e[1];
  float zo[8] = {w0.x, w0.y, w0.z, w0.w, w1.x, w1.y, w1.z, w1.w};
  us8 o;
#pragma unroll
  for (int v = 0; v < 8; ++v)
    o[v] = f2h(fmaxf((zo[v] - lm) - (r[v] - c1) * inv_k, 0.0f));
  *(us8*)(aout + tid * 8) = o;
}

// ---------------------------------------------------------------------------
extern "C" void kernel_launch(void* const* d_in, const int* in_sizes, int n_in,
                              void* d_out, int out_size, void* d_ws, size_t ws_size,
                              hipStream_t stream) {
  const float* x  = (const float*)d_in[0];
  const float* Wq = (const float*)d_in[1];
  const float* Wk = (const float*)d_in[2];
  const float* Wv = (const float*)d_in[3];
  float* out = (float*)d_out;

  const long long NX = (long long)B_ * S_ * D_;   // 8M
  const long long NW = (long long)H_ * D_;        // 1M

  // Workspace layout (total 144 MB + 4 B):
  //  [0,16MB):    x16          -> later Sc (fp32, 64MB, overwrites x16+W)
  //  [16,22MB):   Wq16 Wk16 Wv16 (contiguous, 2MB apart -> fused proj)
  //  [64,80MB):   Vt16 (persists to PV)
  //  [80,96MB):   Q16   [96,112MB): K16   [112,128MB): V16
  //  [80,112MB):  A16 (f16 attention, 32MB; overwrites Q16/K16 after scores)
  //  [144MB]:     flag
  char* base = (char*)d_ws;
  unsigned short* x16  = (unsigned short*)(base);
  unsigned short* Wq16 = (unsigned short*)(base + (16ll << 20));
  unsigned short* Wk16 = (unsigned short*)(base + (18ll << 20));
  unsigned short* Wv16 = (unsigned short*)(base + (20ll << 20));
  float*          Sc   = (float*)(base);
  unsigned short* Vt16 = (unsigned short*)(base + (64ll << 20));
  unsigned short* Q16  = (unsigned short*)(base + (80ll << 20));
  unsigned short* K16  = (unsigned short*)(base + (96ll << 20));
  unsigned short* V16  = (unsigned short*)(base + (112ll << 20));
  unsigned short* A16  = (unsigned short*)(base + (80ll << 20));
  float*          flag = (float*)(base + (144ll << 20));

  hipMemsetAsync(flag, 0, sizeof(float), stream);

  // fused x->f16 + abs-sum (grid-stride)
  f2h_abs_kernel<<<1024, 256, 0, stream>>>(x, x16, flag, (int)(NX / 4));
  // W -> f16, one launch
  f2h3_kernel<<<dim3((int)(NW / 4 + 255) / 256, 3), 256, 0, stream>>>(
      Wq, Wk, Wv, Wq16, Wk16, Wv16, (int)(NW / 4));

  // Projections fused: z selects W (stride 1M elems) and output (stride 8M elems)
  // MI=4 (128x256): 4 x 64 x 3 = 768 blocks
  {
    dim3 grid(H_ / 256, (B_ * S_) / 128, 3);
    gemm8_nt<4, true><<<grid, 512, 0, stream>>>(x16, Wq16, Q16, B_ * S_, H_, D_,
                                                0, (long long)NW, (long long)(8ll << 20),
                                                1.0f);
  }

  // V^T per batch: [S][H] -> [H][S]
  {
    dim3 grid(H_ / 32, S_ / 32, B_);
    transpose_h16<<<grid, dim3(32, 8), 0, stream>>>(V16, Vt16, S_, H_);
  }

  // scores = Q @ K^T / 32 (batched, fp32 out; overwrites x16/W — all dead)
  // MI=8 (256x256): 8 x 8 x 4 = 256 blocks = 1/CU
  {
    dim3 grid(S_ / 256, S_ / 256, B_);
    gemm8_nt<8, false><<<grid, 512, 0, stream>>>(Q16, K16, Sc, S_, S_, H_,
                                                 (long long)S_ * H_, (long long)S_ * H_,
                                                 (long long)S_ * S_, 1.0f / 32.0f);
  }

  // attention = sparsemax-or-softmax(scores) -> f16 (one BLOCK per row)
  attn_row_wave<<<B_ * S_, 256, 0, stream>>>(Sc, A16, flag);

  // out = attention @ Vt^T, f16 MFMA, fp32 out
  // MI=4 (128x256): 4 x 16 x 4 = 256 blocks
  {
    dim3 grid(H_ / 256, S_ / 128, B_);
    gemm8_nt<4, false><<<grid, 512, 0, stream>>>(A16, Vt16, out, S_, H_, S_,
                                                 (long long)S_ * S_, (long long)H_ * S_,
                                                 (long long)S_ * H_, 1.0f);
  }
}

// Round 6
// 335.849 us; speedup vs baseline: 1.0876x; 1.0548x over previous
//
#include <hip/hip_runtime.h>
#include <math.h>

// Problem constants
#define B_   4
#define S_   2048
#define D_   1024
#define H_   1024
#define NROW 2048
#define TOTX 8388608.0f            // B_*S_*D_ elements of x

typedef _Float16 f16x8 __attribute__((ext_vector_type(8)));
typedef float f32x4 __attribute__((ext_vector_type(4)));

__device__ __forceinline__ unsigned short f2h(float f) {
  _Float16 h = (_Float16)f;                       // v_cvt_f16_f32, RNE
  return __builtin_bit_cast(unsigned short, h);
}

// async global->LDS, 16B per lane, lands at ldsbase + lane*16
#define GLD16(gp, lp)                                                            \
  __builtin_amdgcn_global_load_lds(                                              \
      (__attribute__((address_space(1))) void*)(gp),                             \
      (__attribute__((address_space(3))) void*)(lp), 16, 0, 0)

// ---------------------------------------------------------------------------
// fused float->f16 conversion + abs-sum for x (one pass over 32 MB)
// ---------------------------------------------------------------------------
__global__ __launch_bounds__(256) void f2h_abs_kernel(const float* __restrict__ in,
                                                      unsigned short* __restrict__ out,
                                                      float* absOut, int n4) {
  int i0 = blockIdx.x * 256 + threadIdx.x;
  int stride = gridDim.x * 256;
  float s = 0.f;
  for (int i = i0; i < n4; i += stride) {
    float4 v = ((const float4*)in)[i];
    ushort4 o;
    o.x = f2h(v.x); o.y = f2h(v.y); o.z = f2h(v.z); o.w = f2h(v.w);
    ((ushort4*)out)[i] = o;
    s += fabsf(v.x) + fabsf(v.y) + fabsf(v.z) + fabsf(v.w);
  }
#pragma unroll
  for (int off = 32; off; off >>= 1) s += __shfl_xor(s, off);
  __shared__ float red[4];
  if ((threadIdx.x & 63) == 0) red[threadIdx.x >> 6] = s;
  __syncthreads();
  if (threadIdx.x == 0) atomicAdd(absOut, red[0] + red[1] + red[2] + red[3]);
}

// ---------------------------------------------------------------------------
// three weight matrices -> f16 in one launch (blockIdx.y selects matrix)
// ---------------------------------------------------------------------------
__global__ __launch_bounds__(256) void f2h3_kernel(const float* __restrict__ a,
                                                   const float* __restrict__ b,
                                                   const float* __restrict__ c,
                                                   unsigned short* __restrict__ oa,
                                                   unsigned short* __restrict__ ob,
                                                   unsigned short* __restrict__ oc,
                                                   int n4) {
  int i = blockIdx.x * 256 + threadIdx.x;
  if (i >= n4) return;
  const float* in = (blockIdx.y == 0) ? a : (blockIdx.y == 1) ? b : c;
  unsigned short* out = (blockIdx.y == 0) ? oa : (blockIdx.y == 1) ? ob : oc;
  float4 v = ((const float4*)in)[i];
  ushort4 o;
  o.x = f2h(v.x); o.y = f2h(v.y); o.z = f2h(v.z); o.w = f2h(v.w);
  ((ushort4*)out)[i] = o;
}

// ---------------------------------------------------------------------------
// f16 MFMA GEMM NT (round-3 schedule, known good), 8 waves, BN=256,
// BM = MI*32. BK=32, double-buffered LDS with COUNTED vmcnt: tile t+2 is
// staged into the buffer t just vacated (after a read-done barrier), and the
// end-of-iter wait is vmcnt(NLD) -- never 0 in the main loop. 2 barriers/tile.
// New: optional V^T epilogue — when VT != nullptr and blockIdx.z == 2, the
// accumulator's 4 consecutive-m values form a ushort4 of the [b][H][S]
// transposed layout directly (fuses the old transpose kernel away).
// ---------------------------------------------------------------------------
template <int MI, bool OUT_F16>
__global__ __launch_bounds__(512, 2) void gemm8_nt(const unsigned short* __restrict__ A,
                                                   const unsigned short* __restrict__ B,
                                                   void* __restrict__ Cv,
                                                   unsigned short* __restrict__ VT,
                                                   int M, int N, int K,
                                                   long long sA, long long sB, long long sC,
                                                   float scale) {
  constexpr int BM  = MI * 32;          // 256 or 128
  constexpr int ASZ = BM * 32;          // u16 per A tile
  constexpr int BSZ = 256 * 32;         // u16 per B tile
  constexpr int TSZ = ASZ + BSZ;        // u16 per buffer
  constexpr int MH  = MI / 2;           // frags per phase-half

  const int bz = blockIdx.z;
  A += (long long)bz * sA;
  B += (long long)bz * sB;

  __shared__ __align__(16) unsigned short lds[2 * TSZ];

  const int tid = threadIdx.x;
  const int lane = tid & 63;
  const int w = tid >> 6;
  const int wr = w >> 2;          // 0..1 : row band (BM/2 rows)
  const int wc = w & 3;           // 0..3 : 64-col band
  const int m0 = blockIdx.y * BM, n0 = blockIdx.x * 256;

  f32x4 acc[MI][4] = {};

  // staging: 512 threads, lane l of wave w -> row tid>>2 (0..127), chunk swizzle
  const int srow = tid >> 2;
  const int scol = ((lane & 3) ^ ((lane >> 3) & 3)) * 8;
  const unsigned short* gA0 = A + (long long)(m0 + srow) * K + scol;
  const unsigned short* gA1 = gA0 + (long long)128 * K;   // MI==8 only
  const unsigned short* gB0 = B + (long long)(n0 + srow) * K + scol;
  const unsigned short* gB1 = gB0 + (long long)128 * K;
  const int wb = w * 512;

  // fragment read offsets (u16 units), same swizzle family as staging
  const int fm = lane & 15;
  const int col8 = ((lane >> 4) ^ ((lane >> 1) & 3)) * 8;
  int aoff[MI], boff[4];
#pragma unroll
  for (int mi = 0; mi < MI; ++mi) aoff[mi] = (wr * (MI * 16) + mi * 16 + fm) * 32 + col8;
#pragma unroll
  for (int ni = 0; ni < 4; ++ni) boff[ni] = ASZ + (wc * 64 + ni * 16 + fm) * 32 + col8;

  const int nt = K >> 5;

#define STAGE(nb, k0)                                    \
  do {                                                   \
    unsigned short* L_ = lds + (nb) * TSZ;               \
    GLD16(gA0 + (k0), L_ + wb);                          \
    if (MI == 8) GLD16(gA1 + (k0), L_ + 4096 + wb);      \
    GLD16(gB0 + (k0), L_ + ASZ + wb);                    \
    GLD16(gB1 + (k0), L_ + ASZ + 4096 + wb);             \
  } while (0)

  // prologue: stage tiles 0 and 1 (K >= 64 always here)
  STAGE(0, 0);
  STAGE(1, 32);
  if (MI == 8) asm volatile("s_waitcnt vmcnt(4)" ::: "memory");
  else         asm volatile("s_waitcnt vmcnt(3)" ::: "memory");
  __builtin_amdgcn_s_barrier();

  for (int t = 0; t < nt; ++t) {
    const unsigned short* L = lds + (t & 1) * TSZ;
    // half 1: A-lo frags + all B frags, 4*MH MFMAs
    f16x8 af[MH], bf[4];
#pragma unroll
    for (int mi = 0; mi < MH; ++mi) af[mi] = *(const f16x8*)(L + aoff[mi]);
#pragma unroll
    for (int ni = 0; ni < 4; ++ni) bf[ni] = *(const f16x8*)(L + boff[ni]);
    __builtin_amdgcn_s_setprio(1);
#pragma unroll
    for (int mi = 0; mi < MH; ++mi)
#pragma unroll
      for (int ni = 0; ni < 4; ++ni)
        acc[mi][ni] = __builtin_amdgcn_mfma_f32_16x16x32_f16(af[mi], bf[ni],
                                                             acc[mi][ni], 0, 0, 0);
    __builtin_amdgcn_s_setprio(0);
    // half 2 reads, then declare this buffer fully read (barrier)
    f16x8 ag[MH];
#pragma unroll
    for (int mi = 0; mi < MH; ++mi) ag[mi] = *(const f16x8*)(L + aoff[MH + mi]);
    asm volatile("s_waitcnt lgkmcnt(0)" ::: "memory");
    __builtin_amdgcn_sched_barrier(0);
    __builtin_amdgcn_s_barrier();
    // refill the vacated buffer with tile t+2 while computing half 2
    if (t + 2 < nt) STAGE(t & 1, (t + 2) << 5);
    __builtin_amdgcn_s_setprio(1);
#pragma unroll
    for (int mi = 0; mi < MH; ++mi)
#pragma unroll
      for (int ni = 0; ni < 4; ++ni)
        acc[MH + mi][ni] = __builtin_amdgcn_mfma_f32_16x16x32_f16(ag[mi], bf[ni],
                                                                  acc[MH + mi][ni], 0, 0, 0);
    __builtin_amdgcn_s_setprio(0);
    // counted wait: tile t+1 landed, t+2's loads stay in flight
    if (t + 2 < nt) {
      if (MI == 8) asm volatile("s_waitcnt vmcnt(4)" ::: "memory");
      else         asm volatile("s_waitcnt vmcnt(3)" ::: "memory");
    } else if (t + 1 < nt) {
      asm volatile("s_waitcnt vmcnt(0)" ::: "memory");
    }
    __builtin_amdgcn_s_barrier();
  }
#undef STAGE

  // epilogue: C/D layout col=lane&15, row=(lane>>4)*4+reg
  const int cm = (lane >> 4) * 4;
  const int cn = lane & 15;
  if (VT != nullptr && bz == 2) {
    // V^T fused write: m -> (b = m>>11, s = m&2047); 4 consecutive s per frag
#pragma unroll
    for (int mi = 0; mi < MI; ++mi)
#pragma unroll
      for (int ni = 0; ni < 4; ++ni) {
        int m = m0 + wr * (MI * 16) + mi * 16 + cm;
        int n = n0 + wc * 64 + ni * 16 + cn;
        int b = m >> 11, s = m & 2047;
        ushort4 o;
        o.x = f2h(acc[mi][ni][0] * scale);
        o.y = f2h(acc[mi][ni][1] * scale);
        o.z = f2h(acc[mi][ni][2] * scale);
        o.w = f2h(acc[mi][ni][3] * scale);
        *(ushort4*)(VT + (long long)b * (H_ * S_) + (long long)n * S_ + s) = o;
      }
    return;
  }
#pragma unroll
  for (int mi = 0; mi < MI; ++mi)
#pragma unroll
    for (int ni = 0; ni < 4; ++ni) {
#pragma unroll
      for (int r = 0; r < 4; ++r) {
        long long m = m0 + wr * (MI * 16) + mi * 16 + cm + r;
        long long n = n0 + wc * 64 + ni * 16 + cn;
        float v = acc[mi][ni][r] * scale;
        if (OUT_F16)
          ((unsigned short*)Cv)[(long long)bz * sC + m * N + n] = f2h(v);
        else
          ((float*)Cv)[(long long)bz * sC + m * N + n] = v;
      }
    }
}

// ---------------------------------------------------------------------------
// Wave-per-row sparsemax/softmax, element e = lane*32 + v (round-3 v5,
// measured 86 us). NO LDS; per-lane contiguous 128B global chunk; epilogue
// re-reads through a laundered pointer. Bitonic with uniform-sign-flip
// (compile-time descending network) + immediate ds_swizzle cross stages.
// ---------------------------------------------------------------------------
template <int K, int J>
__device__ __forceinline__ void intra_s(float (&r)[32]) {
#pragma unroll
  for (int v = 0; v < 32; ++v)
    if ((v & J) == 0) {
      const int u = v | J;
      const bool dsc = ((v & K) == 0);
      float a = r[v], b = r[u];
      float mx = fmaxf(a, b), mn = fminf(a, b);
      r[v] = dsc ? mx : mn;
      r[u] = dsc ? mn : mx;
    }
}

template <int J>
__device__ __forceinline__ void intra_desc(float (&r)[32]) {
#pragma unroll
  for (int v = 0; v < 32; ++v)
    if ((v & J) == 0) {
      const int u = v | J;
      float a = r[v], b = r[u];
      r[v] = fmaxf(a, b);
      r[u] = fminf(a, b);
    }
}

template <int JL>
__device__ __forceinline__ void cross_desc(float (&r)[32], int lane, int bp32) {
  const bool keepmax = ((lane & JL) == 0);
  float b[32];
#pragma unroll
  for (int v = 0; v < 32; ++v) {
    int av = __builtin_bit_cast(int, r[v]);
    int bv;
    if constexpr (JL == 32)
      bv = __builtin_amdgcn_ds_bpermute(bp32, av);
    else
      bv = __builtin_amdgcn_ds_swizzle(av, (JL << 10) | 0x1F);  // xor-mode
    b[v] = __builtin_bit_cast(float, bv);
  }
  __builtin_amdgcn_sched_barrier(0);   // pin: all swizzles issued before CEs
#pragma unroll
  for (int v = 0; v < 32; ++v) {
    float mx = fmaxf(r[v], b[v]), mn = fminf(r[v], b[v]);
    r[v] = keepmax ? mx : mn;
  }
}

__device__ __forceinline__ void signfix(float (&r)[32], unsigned fix) {
#pragma unroll
  for (int v = 0; v < 32; ++v)
    r[v] = __builtin_bit_cast(float, __builtin_bit_cast(unsigned, r[v]) ^ fix);
}

__global__ __launch_bounds__(256, 4) void attn_row_wave(const float* __restrict__ scores,
                                                        unsigned short* __restrict__ attn,
                                                        const float* __restrict__ absSum) {
  const int tid = threadIdx.x;
  const int lane = tid & 63;
  const int row = blockIdx.x * 4 + (tid >> 6);
  const float* rowp = scores + (long long)row * NROW;
  unsigned short* aout = attn + (long long)row * NROW;
  const int bp32 = (lane ^ 32) << 2;

  // per-lane contiguous 128B chunk: element e = lane*32 + v
  const float4* rp4 = (const float4*)rowp + lane * 8;
  float r[32];
  float lm = -INFINITY, lsraw = 0.f;
#pragma unroll
  for (int q = 0; q < 8; ++q) {
    float4 v = rp4[q];
    r[q * 4 + 0] = v.x; r[q * 4 + 1] = v.y;
    r[q * 4 + 2] = v.z; r[q * 4 + 3] = v.w;
    lm = fmaxf(lm, fmaxf(fmaxf(v.x, v.y), fmaxf(v.z, v.w)));
    lsraw += v.x + v.y + v.z + v.w;
  }
#pragma unroll
  for (int off = 32; off; off >>= 1) {
    lm = fmaxf(lm, __shfl_xor(lm, off, 64));
    lsraw += __shfl_xor(lsraw, off, 64);
  }

  const bool use_softmax = (absSum[0] * (1.0f / TOTX)) >= 1.0f;

  if (use_softmax) {
    float ls = 0.f;
#pragma unroll
    for (int v = 0; v < 32; ++v) { r[v] = expf(r[v] - lm); ls += r[v]; }
#pragma unroll
    for (int off = 32; off; off >>= 1) ls += __shfl_xor(ls, off, 64);
    float inv = 1.0f / ls;
    ushort4* op = (ushort4*)(aout + lane * 32);
#pragma unroll
    for (int q = 0; q < 8; ++q) {
      ushort4 o;
      o.x = f2h(r[q * 4 + 0] * inv); o.y = f2h(r[q * 4 + 1] * inv);
      o.z = f2h(r[q * 4 + 2] * inv); o.w = f2h(r[q * 4 + 3] * inv);
      op[q] = o;
    }
    return;
  }

  // ---- sparsemax ----
#pragma unroll
  for (int v = 0; v < 32; ++v) r[v] -= lm;
  const float step = ((lsraw - (float)NROW * lm) - 1.0f) * (1.0f / (float)NROW);

  // per-lane bitonic presort (compile-time directions)
  intra_s<2, 1>(r);
  intra_s<4, 2>(r); intra_s<4, 1>(r);
  intra_s<8, 4>(r); intra_s<8, 2>(r); intra_s<8, 1>(r);
  intra_s<16, 8>(r); intra_s<16, 4>(r); intra_s<16, 2>(r); intra_s<16, 1>(r);

  // merge ladder with running sign mask (negate-on-!dsc => all merges desc)
  unsigned cur = (unsigned)(lane & 1) << 31;               // kl=1
  signfix(r, cur);
  intra_desc<16>(r); intra_desc<8>(r); intra_desc<4>(r);
  intra_desc<2>(r); intra_desc<1>(r);

  { unsigned want = (unsigned)(lane & 2) << 30;            // kl=2
    signfix(r, cur ^ want); cur = want; }
  cross_desc<1>(r, lane, bp32);
  intra_desc<16>(r); intra_desc<8>(r); intra_desc<4>(r);
  intra_desc<2>(r); intra_desc<1>(r);

  { unsigned want = (unsigned)(lane & 4) << 29;            // kl=4
    signfix(r, cur ^ want); cur = want; }
  cross_desc<2>(r, lane, bp32); cross_desc<1>(r, lane, bp32);
  intra_desc<16>(r); intra_desc<8>(r); intra_desc<4>(r);
  intra_desc<2>(r); intra_desc<1>(r);

  { unsigned want = (unsigned)(lane & 8) << 28;            // kl=8
    signfix(r, cur ^ want); cur = want; }
  cross_desc<4>(r, lane, bp32); cross_desc<2>(r, lane, bp32);
  cross_desc<1>(r, lane, bp32);
  intra_desc<16>(r); intra_desc<8>(r); intra_desc<4>(r);
  intra_desc<2>(r); intra_desc<1>(r);

  { unsigned want = (unsigned)(lane & 16) << 27;           // kl=16
    signfix(r, cur ^ want); cur = want; }
  cross_desc<8>(r, lane, bp32); cross_desc<4>(r, lane, bp32);
  cross_desc<2>(r, lane, bp32); cross_desc<1>(r, lane, bp32);
  intra_desc<16>(r); intra_desc<8>(r); intra_desc<4>(r);
  intra_desc<2>(r); intra_desc<1>(r);

  { unsigned want = (unsigned)(lane & 32) << 26;           // kl=32
    signfix(r, cur ^ want); cur = want; }
  cross_desc<16>(r, lane, bp32); cross_desc<8>(r, lane, bp32);
  cross_desc<4>(r, lane, bp32); cross_desc<2>(r, lane, bp32);
  cross_desc<1>(r, lane, bp32);
  intra_desc<16>(r); intra_desc<8>(r); intra_desc<4>(r);
  intra_desc<2>(r); intra_desc<1>(r);

  signfix(r, cur);                                         // kl=64: dsc==true everywhere
  cross_desc<32>(r, lane, bp32); cross_desc<16>(r, lane, bp32);
  cross_desc<8>(r, lane, bp32); cross_desc<4>(r, lane, bp32);
  cross_desc<2>(r, lane, bp32); cross_desc<1>(r, lane, bp32);
  intra_desc<16>(r); intra_desc<8>(r); intra_desc<4>(r);
  intra_desc<2>(r); intra_desc<1>(r);

  // k = count(sorted > step)
  float lcnt = 0.f;
#pragma unroll
  for (int v = 0; v < 32; ++v) lcnt += (r[v] > step) ? 1.0f : 0.0f;
#pragma unroll
  for (int off = 32; off; off >>= 1) lcnt += __shfl_xor(lcnt, off, 64);
  const float kf = lcnt;

  // inclusive cumsum over e: local sequential + wave scan of lane totals
  float run = 0.f;
#pragma unroll
  for (int v = 0; v < 32; ++v) { run += r[v]; r[v] = run; }
  float pre = run;
#pragma unroll
  for (int off = 1; off < 64; off <<= 1) {
    float t = __shfl_up(pre, off, 64);
    if (lane >= off) pre += t;
  }
  pre -= run;  // exclusive prefix of lane totals
#pragma unroll
  for (int v = 0; v < 32; ++v) r[v] += pre;

  const float inv_k = 1.0f / kf;
  const float c1 = 1.0f + step * kf;

  // epilogue: re-read original z through a laundered pointer (blocks CSE of
  // the first-pass loads across the whole sort -> no 32-reg live range)
  unsigned long long up = (unsigned long long)rowp;
  asm volatile("" : "+v"(up));
  const float4* rp4e = (const float4*)up + lane * 8;
  ushort4* op = (ushort4*)(aout + lane * 32);
#pragma unroll
  for (int q = 0; q < 8; ++q) {
    float4 v = rp4e[q];
    ushort4 o;
    o.x = f2h(fmaxf((v.x - lm) - (r[q * 4 + 0] - c1) * inv_k, 0.0f));
    o.y = f2h(fmaxf((v.y - lm) - (r[q * 4 + 1] - c1) * inv_k, 0.0f));
    o.z = f2h(fmaxf((v.z - lm) - (r[q * 4 + 2] - c1) * inv_k, 0.0f));
    o.w = f2h(fmaxf((v.w - lm) - (r[q * 4 + 3] - c1) * inv_k, 0.0f));
    op[q] = o;
  }
}

// ---------------------------------------------------------------------------
extern "C" void kernel_launch(void* const* d_in, const int* in_sizes, int n_in,
                              void* d_out, int out_size, void* d_ws, size_t ws_size,
                              hipStream_t stream) {
  const float* x  = (const float*)d_in[0];
  const float* Wq = (const float*)d_in[1];
  const float* Wk = (const float*)d_in[2];
  const float* Wv = (const float*)d_in[3];
  float* out = (float*)d_out;

  const long long NX = (long long)B_ * S_ * D_;   // 8M
  const long long NW = (long long)H_ * D_;        // 1M

  // Workspace layout (total 144 MB + 4 B):
  //  [0,16MB):    x16          -> later Sc (fp32, 64MB, overwrites x16+W)
  //  [16,22MB):   Wq16 Wk16 Wv16 (contiguous, 2MB apart -> fused proj)
  //  [64,80MB):   Vt16 (written directly by proj epilogue; persists to PV)
  //  [80,96MB):   Q16   [96,112MB): K16
  //  [80,112MB):  A16 (f16 attention, 32MB; overwrites Q16/K16 after scores)
  //  [144MB]:     flag
  char* base = (char*)d_ws;
  unsigned short* x16  = (unsigned short*)(base);
  unsigned short* Wq16 = (unsigned short*)(base + (16ll << 20));
  unsigned short* Wk16 = (unsigned short*)(base + (18ll << 20));
  unsigned short* Wv16 = (unsigned short*)(base + (20ll << 20));
  float*          Sc   = (float*)(base);
  unsigned short* Vt16 = (unsigned short*)(base + (64ll << 20));
  unsigned short* Q16  = (unsigned short*)(base + (80ll << 20));
  unsigned short* K16  = (unsigned short*)(base + (96ll << 20));
  unsigned short* A16  = (unsigned short*)(base + (80ll << 20));
  float*          flag = (float*)(base + (144ll << 20));

  hipMemsetAsync(flag, 0, sizeof(float), stream);

  // fused x->f16 + abs-sum (grid-stride)
  f2h_abs_kernel<<<1024, 256, 0, stream>>>(x, x16, flag, (int)(NX / 4));
  // W -> f16, one launch
  f2h3_kernel<<<dim3((int)(NW / 4 + 255) / 256, 3), 256, 0, stream>>>(
      Wq, Wk, Wv, Wq16, Wk16, Wv16, (int)(NW / 4));

  // Projections fused: z selects W (stride 1M) and output (stride 8M elems);
  // z==2 (V) writes transposed [b][H][S] directly via the VT epilogue.
  // MI=4 (128x256): 4 x 64 x 3 = 768 blocks, 2 blocks/CU
  {
    dim3 grid(H_ / 256, (B_ * S_) / 128, 3);
    gemm8_nt<4, true><<<grid, 512, 0, stream>>>(x16, Wq16, Q16, Vt16,
                                                B_ * S_, H_, D_,
                                                0, (long long)NW, (long long)(8ll << 20),
                                                1.0f);
  }

  // scores = Q @ K^T / 32 (batched, fp32 out; overwrites x16/W — all dead)
  // MI=4 (128x256): 8 x 16 x 4 = 512 blocks, 2 blocks/CU (was 1 at MI=8)
  {
    dim3 grid(S_ / 256, S_ / 128, B_);
    gemm8_nt<4, false><<<grid, 512, 0, stream>>>(Q16, K16, Sc, nullptr,
                                                 S_, S_, H_,
                                                 (long long)S_ * H_, (long long)S_ * H_,
                                                 (long long)S_ * S_, 1.0f / 32.0f);
  }

  // attention = sparsemax-or-softmax(scores) -> f16 (one wave per row)
  attn_row_wave<<<(B_ * S_) / 4, 256, 0, stream>>>(Sc, A16, flag);

  // out = attention @ Vt^T, f16 MFMA, fp32 out
  // MI=4 (128x256): 4 x 16 x 4 = 256 blocks, 2 blocks/CU
  {
    dim3 grid(H_ / 256, S_ / 128, B_);
    gemm8_nt<4, false><<<grid, 512, 0, stream>>>(A16, Vt16, out, nullptr,
                                                 S_, H_, S_,
                                                 (long long)S_ * S_, (long long)H_ * S_,
                                                 (long long)S_ * H_, 1.0f);
  }
}

// Round 7
// 314.267 us; speedup vs baseline: 1.1623x; 1.0687x over previous
//
#include <hip/hip_runtime.h>
#include <math.h>

// Problem constants
#define B_   4
#define S_   2048
#define D_   1024
#define H_   1024
#define NROW 2048
#define TOTX 8388608.0f            // B_*S_*D_ elements of x

typedef _Float16 f16x8 __attribute__((ext_vector_type(8)));
typedef float f32x4 __attribute__((ext_vector_type(4)));
typedef unsigned short us8 __attribute__((ext_vector_type(8)));

__device__ __forceinline__ unsigned short f2h(float f) {
  _Float16 h = (_Float16)f;                       // v_cvt_f16_f32, RNE
  return __builtin_bit_cast(unsigned short, h);
}
__device__ __forceinline__ float h2f(unsigned short u) {
  return (float)__builtin_bit_cast(_Float16, u);  // v_cvt_f32_f16
}

// async global->LDS, 16B per lane, lands at ldsbase + lane*16
#define GLD16(gp, lp)                                                            \
  __builtin_amdgcn_global_load_lds(                                              \
      (__attribute__((address_space(1))) void*)(gp),                             \
      (__attribute__((address_space(3))) void*)(lp), 16, 0, 0)

// ---------------------------------------------------------------------------
// fused float->f16 conversion + abs-sum for x (one pass over 32 MB)
// ---------------------------------------------------------------------------
__global__ __launch_bounds__(256) void f2h_abs_kernel(const float* __restrict__ in,
                                                      unsigned short* __restrict__ out,
                                                      float* absOut, int n4) {
  int i0 = blockIdx.x * 256 + threadIdx.x;
  int stride = gridDim.x * 256;
  float s = 0.f;
  for (int i = i0; i < n4; i += stride) {
    float4 v = ((const float4*)in)[i];
    ushort4 o;
    o.x = f2h(v.x); o.y = f2h(v.y); o.z = f2h(v.z); o.w = f2h(v.w);
    ((ushort4*)out)[i] = o;
    s += fabsf(v.x) + fabsf(v.y) + fabsf(v.z) + fabsf(v.w);
  }
#pragma unroll
  for (int off = 32; off; off >>= 1) s += __shfl_xor(s, off);
  __shared__ float red[4];
  if ((threadIdx.x & 63) == 0) red[threadIdx.x >> 6] = s;
  __syncthreads();
  if (threadIdx.x == 0) atomicAdd(absOut, red[0] + red[1] + red[2] + red[3]);
}

// ---------------------------------------------------------------------------
// three weight matrices -> f16 in one launch (blockIdx.y selects matrix)
// ---------------------------------------------------------------------------
__global__ __launch_bounds__(256) void f2h3_kernel(const float* __restrict__ a,
                                                   const float* __restrict__ b,
                                                   const float* __restrict__ c,
                                                   unsigned short* __restrict__ oa,
                                                   unsigned short* __restrict__ ob,
                                                   unsigned short* __restrict__ oc,
                                                   int n4) {
  int i = blockIdx.x * 256 + threadIdx.x;
  if (i >= n4) return;
  const float* in = (blockIdx.y == 0) ? a : (blockIdx.y == 1) ? b : c;
  unsigned short* out = (blockIdx.y == 0) ? oa : (blockIdx.y == 1) ? ob : oc;
  float4 v = ((const float4*)in)[i];
  ushort4 o;
  o.x = f2h(v.x); o.y = f2h(v.y); o.z = f2h(v.z); o.w = f2h(v.w);
  ((ushort4*)out)[i] = o;
}

// ---------------------------------------------------------------------------
// f16 MFMA GEMM NT, 8 waves, BN=256, BM = MI*32. BK=32, TRIPLE-buffered LDS,
// SINGLE barrier per K-tile:
//   { issue all 8 ds_read_b128 (af+bf) | issue GLDs for tile t+2 into the
//     third buffer -> lgkmcnt(0) -> 16/32 MFMA -> vmcnt(NLD) -> s_barrier }
// vmcnt(NLD) waits for tile t+1 (issued 2 iters ago, fully hidden under MFMA);
// never 0 in the main loop. Buffer (t+2)%3 was last read at t-1 and those
// reads completed before t-1's barrier (lgkm0 precedes MFMA) -> WAR safe.
// Optional V^T epilogue (blockIdx.z==2): acc's 4 consecutive-m values form a
// ushort4 of the transposed [b][H][S] layout directly.
// ---------------------------------------------------------------------------
template <int MI, bool OUT_F16>
__global__ __launch_bounds__(512, 2) void gemm8_nt(const unsigned short* __restrict__ A,
                                                   const unsigned short* __restrict__ B,
                                                   void* __restrict__ Cv,
                                                   unsigned short* __restrict__ VT,
                                                   int M, int N, int K,
                                                   long long sA, long long sB, long long sC,
                                                   float scale) {
  constexpr int BM  = MI * 32;          // 256 or 128
  constexpr int ASZ = BM * 32;          // u16 per A tile
  constexpr int BSZ = 256 * 32;         // u16 per B tile
  constexpr int TSZ = ASZ + BSZ;        // u16 per buffer

  const int bz = blockIdx.z;
  A += (long long)bz * sA;
  B += (long long)bz * sB;

  __shared__ __align__(16) unsigned short lds[3 * TSZ];

  const int tid = threadIdx.x;
  const int lane = tid & 63;
  const int w = tid >> 6;
  const int wr = w >> 2;          // 0..1 : row band (BM/2 rows)
  const int wc = w & 3;           // 0..3 : 64-col band
  const int m0 = blockIdx.y * BM, n0 = blockIdx.x * 256;

  f32x4 acc[MI][4] = {};

  // staging: 512 threads, lane l of wave w -> row tid>>2 (0..127), chunk swizzle
  const int srow = tid >> 2;
  const int scol = ((lane & 3) ^ ((lane >> 3) & 3)) * 8;
  const unsigned short* gA0 = A + (long long)(m0 + srow) * K + scol;
  const unsigned short* gA1 = gA0 + (long long)128 * K;   // MI==8 only
  const unsigned short* gB0 = B + (long long)(n0 + srow) * K + scol;
  const unsigned short* gB1 = gB0 + (long long)128 * K;
  const int wb = w * 512;

  // fragment read offsets (u16 units), same swizzle family as staging
  const int fm = lane & 15;
  const int col8 = ((lane >> 4) ^ ((lane >> 1) & 3)) * 8;
  int aoff[MI], boff[4];
#pragma unroll
  for (int mi = 0; mi < MI; ++mi) aoff[mi] = (wr * (MI * 16) + mi * 16 + fm) * 32 + col8;
#pragma unroll
  for (int ni = 0; ni < 4; ++ni) boff[ni] = ASZ + (wc * 64 + ni * 16 + fm) * 32 + col8;

  const int nt = K >> 5;

#define STAGEP(Lp, k0)                                   \
  do {                                                   \
    GLD16(gA0 + (k0), (Lp) + wb);                        \
    if (MI == 8) GLD16(gA1 + (k0), (Lp) + 4096 + wb);    \
    GLD16(gB0 + (k0), (Lp) + ASZ + wb);                  \
    GLD16(gB1 + (k0), (Lp) + ASZ + 4096 + wb);           \
  } while (0)

  unsigned short* L0 = lds;
  unsigned short* L1 = lds + TSZ;
  unsigned short* L2 = lds + 2 * TSZ;

  // prologue: tile0 -> buf0, tile1 -> buf1; wait tile0 landed (tile1 in flight)
  STAGEP(L0, 0);
  STAGEP(L1, 32);
  if (MI == 8) asm volatile("s_waitcnt vmcnt(4)" ::: "memory");
  else         asm volatile("s_waitcnt vmcnt(3)" ::: "memory");
  __builtin_amdgcn_s_barrier();

  for (int t = 0; t < nt; ++t) {
    // issue all fragment reads for this tile
    f16x8 af[MI], bf[4];
#pragma unroll
    for (int mi = 0; mi < MI; ++mi) af[mi] = *(const f16x8*)(L0 + aoff[mi]);
#pragma unroll
    for (int ni = 0; ni < 4; ++ni) bf[ni] = *(const f16x8*)(L0 + boff[ni]);
    // issue staging for tile t+2 into the free buffer
    if (t + 2 < nt) STAGEP(L2, (t + 2) << 5);
    asm volatile("s_waitcnt lgkmcnt(0)" ::: "memory");
    __builtin_amdgcn_sched_barrier(0);
    __builtin_amdgcn_s_setprio(1);
#pragma unroll
    for (int mi = 0; mi < MI; ++mi)
#pragma unroll
      for (int ni = 0; ni < 4; ++ni)
        acc[mi][ni] = __builtin_amdgcn_mfma_f32_16x16x32_f16(af[mi], bf[ni],
                                                             acc[mi][ni], 0, 0, 0);
    __builtin_amdgcn_s_setprio(0);
    // counted wait: tile t+1 landed (issued 2 iters ago), t+2 stays in flight
    if (t + 2 < nt) {
      if (MI == 8) asm volatile("s_waitcnt vmcnt(4)" ::: "memory");
      else         asm volatile("s_waitcnt vmcnt(3)" ::: "memory");
    } else if (t + 1 < nt) {
      asm volatile("s_waitcnt vmcnt(0)" ::: "memory");
    }
    __builtin_amdgcn_s_barrier();
    unsigned short* tmp = L0; L0 = L1; L1 = L2; L2 = tmp;
  }
#undef STAGEP

  // epilogue: C/D layout col=lane&15, row=(lane>>4)*4+reg
  const int cm = (lane >> 4) * 4;
  const int cn = lane & 15;
  if (VT != nullptr && bz == 2) {
    // V^T fused write: m -> (b = m>>11, s = m&2047); 4 consecutive s per frag
#pragma unroll
    for (int mi = 0; mi < MI; ++mi)
#pragma unroll
      for (int ni = 0; ni < 4; ++ni) {
        int m = m0 + wr * (MI * 16) + mi * 16 + cm;
        int n = n0 + wc * 64 + ni * 16 + cn;
        int b = m >> 11, s = m & 2047;
        ushort4 o;
        o.x = f2h(acc[mi][ni][0] * scale);
        o.y = f2h(acc[mi][ni][1] * scale);
        o.z = f2h(acc[mi][ni][2] * scale);
        o.w = f2h(acc[mi][ni][3] * scale);
        *(ushort4*)(VT + (long long)b * (H_ * S_) + (long long)n * S_ + s) = o;
      }
    return;
  }
#pragma unroll
  for (int mi = 0; mi < MI; ++mi)
#pragma unroll
    for (int ni = 0; ni < 4; ++ni) {
#pragma unroll
      for (int r = 0; r < 4; ++r) {
        long long m = m0 + wr * (MI * 16) + mi * 16 + cm + r;
        long long n = n0 + wc * 64 + ni * 16 + cn;
        float v = acc[mi][ni][r] * scale;
        if (OUT_F16)
          ((unsigned short*)Cv)[(long long)bz * sC + m * N + n] = f2h(v);
        else
          ((float*)Cv)[(long long)bz * sC + m * N + n] = v;
      }
    }
}

// ---------------------------------------------------------------------------
// Wave-per-row sparsemax/softmax, element e = lane*32 + v. Scores now f16
// (halves score-read traffic); all math still f32 on the converted values —
// exact sparsemax of the rounded inputs. Sort network unchanged (known-good).
// ---------------------------------------------------------------------------
template <int K, int J>
__device__ __forceinline__ void intra_s(float (&r)[32]) {
#pragma unroll
  for (int v = 0; v < 32; ++v)
    if ((v & J) == 0) {
      const int u = v | J;
      const bool dsc = ((v & K) == 0);
      float a = r[v], b = r[u];
      float mx = fmaxf(a, b), mn = fminf(a, b);
      r[v] = dsc ? mx : mn;
      r[u] = dsc ? mn : mx;
    }
}

template <int J>
__device__ __forceinline__ void intra_desc(float (&r)[32]) {
#pragma unroll
  for (int v = 0; v < 32; ++v)
    if ((v & J) == 0) {
      const int u = v | J;
      float a = r[v], b = r[u];
      r[v] = fmaxf(a, b);
      r[u] = fminf(a, b);
    }
}

template <int JL>
__device__ __forceinline__ void cross_desc(float (&r)[32], int lane, int bp32) {
  const bool keepmax = ((lane & JL) == 0);
  float b[32];
#pragma unroll
  for (int v = 0; v < 32; ++v) {
    int av = __builtin_bit_cast(int, r[v]);
    int bv;
    if constexpr (JL == 32)
      bv = __builtin_amdgcn_ds_bpermute(bp32, av);
    else
      bv = __builtin_amdgcn_ds_swizzle(av, (JL << 10) | 0x1F);  // xor-mode
    b[v] = __builtin_bit_cast(float, bv);
  }
  __builtin_amdgcn_sched_barrier(0);   // pin: all swizzles issued before CEs
#pragma unroll
  for (int v = 0; v < 32; ++v) {
    float mx = fmaxf(r[v], b[v]), mn = fminf(r[v], b[v]);
    r[v] = keepmax ? mx : mn;
  }
}

__device__ __forceinline__ void signfix(float (&r)[32], unsigned fix) {
#pragma unroll
  for (int v = 0; v < 32; ++v)
    r[v] = __builtin_bit_cast(float, __builtin_bit_cast(unsigned, r[v]) ^ fix);
}

__global__ __launch_bounds__(256, 4) void attn_row_wave(const unsigned short* __restrict__ scores,
                                                        unsigned short* __restrict__ attn,
                                                        const float* __restrict__ absSum) {
  const int tid = threadIdx.x;
  const int lane = tid & 63;
  const int row = blockIdx.x * 4 + (tid >> 6);
  const unsigned short* rowp = scores + (long long)row * NROW;
  unsigned short* aout = attn + (long long)row * NROW;
  const int bp32 = (lane ^ 32) << 2;

  // per-lane contiguous 64B chunk of f16 scores: element e = lane*32 + v
  const us8* rp = (const us8*)(rowp + lane * 32);
  float r[32];
  float lm = -INFINITY, lsraw = 0.f;
#pragma unroll
  for (int q = 0; q < 4; ++q) {
    us8 h = rp[q];
#pragma unroll
    for (int j = 0; j < 8; ++j) {
      float f = h2f((unsigned short)h[j]);
      r[q * 8 + j] = f;
      lm = fmaxf(lm, f);
      lsraw += f;
    }
  }
#pragma unroll
  for (int off = 32; off; off >>= 1) {
    lm = fmaxf(lm, __shfl_xor(lm, off, 64));
    lsraw += __shfl_xor(lsraw, off, 64);
  }

  const bool use_softmax = (absSum[0] * (1.0f / TOTX)) >= 1.0f;

  if (use_softmax) {
    float ls = 0.f;
#pragma unroll
    for (int v = 0; v < 32; ++v) { r[v] = expf(r[v] - lm); ls += r[v]; }
#pragma unroll
    for (int off = 32; off; off >>= 1) ls += __shfl_xor(ls, off, 64);
    float inv = 1.0f / ls;
    us8* op = (us8*)(aout + lane * 32);
#pragma unroll
    for (int q = 0; q < 4; ++q) {
      us8 o;
#pragma unroll
      for (int j = 0; j < 8; ++j) o[j] = f2h(r[q * 8 + j] * inv);
      op[q] = o;
    }
    return;
  }

  // ---- sparsemax ----
#pragma unroll
  for (int v = 0; v < 32; ++v) r[v] -= lm;
  const float step = ((lsraw - (float)NROW * lm) - 1.0f) * (1.0f / (float)NROW);

  // per-lane bitonic presort (compile-time directions)
  intra_s<2, 1>(r);
  intra_s<4, 2>(r); intra_s<4, 1>(r);
  intra_s<8, 4>(r); intra_s<8, 2>(r); intra_s<8, 1>(r);
  intra_s<16, 8>(r); intra_s<16, 4>(r); intra_s<16, 2>(r); intra_s<16, 1>(r);

  // merge ladder with running sign mask (negate-on-!dsc => all merges desc)
  unsigned cur = (unsigned)(lane & 1) << 31;               // kl=1
  signfix(r, cur);
  intra_desc<16>(r); intra_desc<8>(r); intra_desc<4>(r);
  intra_desc<2>(r); intra_desc<1>(r);

  { unsigned want = (unsigned)(lane & 2) << 30;            // kl=2
    signfix(r, cur ^ want); cur = want; }
  cross_desc<1>(r, lane, bp32);
  intra_desc<16>(r); intra_desc<8>(r); intra_desc<4>(r);
  intra_desc<2>(r); intra_desc<1>(r);

  { unsigned want = (unsigned)(lane & 4) << 29;            // kl=4
    signfix(r, cur ^ want); cur = want; }
  cross_desc<2>(r, lane, bp32); cross_desc<1>(r, lane, bp32);
  intra_desc<16>(r); intra_desc<8>(r); intra_desc<4>(r);
  intra_desc<2>(r); intra_desc<1>(r);

  { unsigned want = (unsigned)(lane & 8) << 28;            // kl=8
    signfix(r, cur ^ want); cur = want; }
  cross_desc<4>(r, lane, bp32); cross_desc<2>(r, lane, bp32);
  cross_desc<1>(r, lane, bp32);
  intra_desc<16>(r); intra_desc<8>(r); intra_desc<4>(r);
  intra_desc<2>(r); intra_desc<1>(r);

  { unsigned want = (unsigned)(lane & 16) << 27;           // kl=16
    signfix(r, cur ^ want); cur = want; }
  cross_desc<8>(r, lane, bp32); cross_desc<4>(r, lane, bp32);
  cross_desc<2>(r, lane, bp32); cross_desc<1>(r, lane, bp32);
  intra_desc<16>(r); intra_desc<8>(r); intra_desc<4>(r);
  intra_desc<2>(r); intra_desc<1>(r);

  { unsigned want = (unsigned)(lane & 32) << 26;           // kl=32
    signfix(r, cur ^ want); cur = want; }
  cross_desc<16>(r, lane, bp32); cross_desc<8>(r, lane, bp32);
  cross_desc<4>(r, lane, bp32); cross_desc<2>(r, lane, bp32);
  cross_desc<1>(r, lane, bp32);
  intra_desc<16>(r); intra_desc<8>(r); intra_desc<4>(r);
  intra_desc<2>(r); intra_desc<1>(r);

  signfix(r, cur);                                         // kl=64: dsc==true everywhere
  cross_desc<32>(r, lane, bp32); cross_desc<16>(r, lane, bp32);
  cross_desc<8>(r, lane, bp32); cross_desc<4>(r, lane, bp32);
  cross_desc<2>(r, lane, bp32); cross_desc<1>(r, lane, bp32);
  intra_desc<16>(r); intra_desc<8>(r); intra_desc<4>(r);
  intra_desc<2>(r); intra_desc<1>(r);

  // k = count(sorted > step)
  float lcnt = 0.f;
#pragma unroll
  for (int v = 0; v < 32; ++v) lcnt += (r[v] > step) ? 1.0f : 0.0f;
#pragma unroll
  for (int off = 32; off; off >>= 1) lcnt += __shfl_xor(lcnt, off, 64);
  const float kf = lcnt;

  // inclusive cumsum over e: local sequential + wave scan of lane totals
  float run = 0.f;
#pragma unroll
  for (int v = 0; v < 32; ++v) { run += r[v]; r[v] = run; }
  float pre = run;
#pragma unroll
  for (int off = 1; off < 64; off <<= 1) {
    float t = __shfl_up(pre, off, 64);
    if (lane >= off) pre += t;
  }
  pre -= run;  // exclusive prefix of lane totals
#pragma unroll
  for (int v = 0; v < 32; ++v) r[v] += pre;

  const float inv_k = 1.0f / kf;
  const float c1 = 1.0f + step * kf;

  // epilogue: re-read original f16 z through a laundered pointer (blocks CSE
  // of the first-pass loads across the whole sort -> no 32-reg live range)
  unsigned long long up = (unsigned long long)rowp;
  asm volatile("" : "+v"(up));
  const us8* rpe = (const us8*)up + lane * 4;
  us8* op = (us8*)(aout + lane * 32);
#pragma unroll
  for (int q = 0; q < 4; ++q) {
    us8 h = rpe[q];
    us8 o;
#pragma unroll
    for (int j = 0; j < 8; ++j) {
      float z = h2f((unsigned short)h[j]) - lm;
      o[j] = f2h(fmaxf(z - (r[q * 8 + j] - c1) * inv_k, 0.0f));
    }
    op[q] = o;
  }
}

// ---------------------------------------------------------------------------
extern "C" void kernel_launch(void* const* d_in, const int* in_sizes, int n_in,
                              void* d_out, int out_size, void* d_ws, size_t ws_size,
                              hipStream_t stream) {
  const float* x  = (const float*)d_in[0];
  const float* Wq = (const float*)d_in[1];
  const float* Wk = (const float*)d_in[2];
  const float* Wv = (const float*)d_in[3];
  float* out = (float*)d_out;

  const long long NX = (long long)B_ * S_ * D_;   // 8M
  const long long NW = (long long)H_ * D_;        // 1M

  // Workspace layout (total 144 MB + 4 B):
  //  [0,16MB):    x16          -> later Sc16 (f16 scores, 32MB, overwrites x16+W)
  //  [16,22MB):   Wq16 Wk16 Wv16 (contiguous, 2MB apart -> fused proj)
  //  [64,80MB):   Vt16 (written directly by proj epilogue; persists to PV)
  //  [80,96MB):   Q16   [96,112MB): K16
  //  [80,112MB):  A16 (f16 attention, 32MB; overwrites Q16/K16 after scores)
  //  [144MB]:     flag
  char* base = (char*)d_ws;
  unsigned short* x16  = (unsigned short*)(base);
  unsigned short* Wq16 = (unsigned short*)(base + (16ll << 20));
  unsigned short* Wk16 = (unsigned short*)(base + (18ll << 20));
  unsigned short* Wv16 = (unsigned short*)(base + (20ll << 20));
  unsigned short* Sc16 = (unsigned short*)(base);
  unsigned short* Vt16 = (unsigned short*)(base + (64ll << 20));
  unsigned short* Q16  = (unsigned short*)(base + (80ll << 20));
  unsigned short* K16  = (unsigned short*)(base + (96ll << 20));
  unsigned short* A16  = (unsigned short*)(base + (80ll << 20));
  float*          flag = (float*)(base + (144ll << 20));

  hipMemsetAsync(flag, 0, sizeof(float), stream);

  // fused x->f16 + abs-sum (grid-stride)
  f2h_abs_kernel<<<1024, 256, 0, stream>>>(x, x16, flag, (int)(NX / 4));
  // W -> f16, one launch
  f2h3_kernel<<<dim3((int)(NW / 4 + 255) / 256, 3), 256, 0, stream>>>(
      Wq, Wk, Wv, Wq16, Wk16, Wv16, (int)(NW / 4));

  // Projections fused: z selects W (stride 1M) and output (stride 8M elems);
  // z==2 (V) writes transposed [b][H][S] directly via the VT epilogue.
  // MI=4 (128x256): 4 x 64 x 3 = 768 blocks, 2 blocks/CU
  {
    dim3 grid(H_ / 256, (B_ * S_) / 128, 3);
    gemm8_nt<4, true><<<grid, 512, 0, stream>>>(x16, Wq16, Q16, Vt16,
                                                B_ * S_, H_, D_,
                                                0, (long long)NW, (long long)(8ll << 20),
                                                1.0f);
  }

  // scores = Q @ K^T / 32 (batched, f16 out; overwrites x16/W — all dead)
  // MI=4 (128x256): 8 x 16 x 4 = 512 blocks, 2 blocks/CU
  {
    dim3 grid(S_ / 256, S_ / 128, B_);
    gemm8_nt<4, true><<<grid, 512, 0, stream>>>(Q16, K16, Sc16, nullptr,
                                                S_, S_, H_,
                                                (long long)S_ * H_, (long long)S_ * H_,
                                                (long long)S_ * S_, 1.0f / 32.0f);
  }

  // attention = sparsemax-or-softmax(scores) -> f16 (one wave per row)
  attn_row_wave<<<(B_ * S_) / 4, 256, 0, stream>>>(Sc16, A16, flag);

  // out = attention @ Vt^T, f16 MFMA, fp32 out
  // MI=4 (128x256): 4 x 16 x 4 = 256 blocks, 2 blocks/CU
  {
    dim3 grid(H_ / 256, S_ / 128, B_);
    gemm8_nt<4, false><<<grid, 512, 0, stream>>>(A16, Vt16, out, nullptr,
                                                 S_, H_, S_,
                                                 (long long)S_ * S_, (long long)H_ * S_,
                                                 (long long)S_ * H_, 1.0f);
  }
}